// Round 19
// baseline (288.718 us; speedup 1.0000x reference)
//
#include <hip/hip_runtime.h>
#include <hip/hip_bf16.h>
#include <math.h>

// Problem constants (from reference)
#define B_  64
#define P_  100
#define N_  1000
#define EMB_ 256
#define H_  16
#define D_  16
#define CTX_ 1024
#define L2E 1.44269504088896340736f

#if __has_builtin(__builtin_amdgcn_exp2f)
#define EXP2F(x) __builtin_amdgcn_exp2f(x)
#else
#define EXP2F(x) exp2f(x)
#endif

typedef __bf16 bf16_t;
typedef bf16_t bf16x8 __attribute__((ext_vector_type(8)));
typedef bf16_t bf16x4 __attribute__((ext_vector_type(4)));
typedef float  f32x4  __attribute__((ext_vector_type(4)));
typedef short  s16x4  __attribute__((ext_vector_type(4)));

// PV MFMA via builtin when available (R16-proven correct/neutral);
// asm fallback with manual hazard fences otherwise.
#if __has_builtin(__builtin_amdgcn_mfma_f32_16x16x16bf16_1k)
__device__ __forceinline__ void pv_mfma16(bf16x4 a, bf16x4 b, f32x4& c)
{
    s16x4 ai, bi;
    __builtin_memcpy(&ai, &a, 8);
    __builtin_memcpy(&bi, &b, 8);
    c = __builtin_amdgcn_mfma_f32_16x16x16bf16_1k(ai, bi, c, 0, 0, 0);
}
__device__ __forceinline__ void mfma_hazard_fence() {}
#else
__device__ __forceinline__ void pv_mfma16(bf16x4 a, bf16x4 b, f32x4& c)
{
    asm("s_nop 1\n\tv_mfma_f32_16x16x16_bf16 %0, %1, %2, %0"
        : "+v"(c) : "v"(a), "v"(b));
}
__device__ __forceinline__ void mfma_hazard_fence()
{
    __builtin_amdgcn_sched_barrier(0);
    asm volatile("s_nop 7\n\ts_nop 3");
}
#endif

// Load 8 consecutive f32 and convert to bf16x8 in-register.
__device__ __forceinline__ bf16x8 ldcvt8(const float* __restrict__ p)
{
    float4 u = *(const float4*)p;
    float4 v = *(const float4*)(p + 4);
    bf16x8 r;
    r[0] = (bf16_t)u.x; r[1] = (bf16_t)u.y; r[2] = (bf16_t)u.z; r[3] = (bf16_t)u.w;
    r[4] = (bf16_t)v.x; r[5] = (bf16_t)v.y; r[6] = (bf16_t)v.z; r[7] = (bf16_t)v.w;
    return r;
}

// ---------------------------------------------------------------------------
// Transpose four 256x256 f32 weights -> bf16 WT[n][k]
// ---------------------------------------------------------------------------
__global__ __launch_bounds__(256) void wtrans_kernel(
    const float* __restrict__ W0, const float* __restrict__ W1,
    const float* __restrict__ W2, const float* __restrict__ W3,
    bf16_t* __restrict__ T0, bf16_t* __restrict__ T1,
    bf16_t* __restrict__ T2, bf16_t* __restrict__ T3)
{
    __shared__ float t[32][33];
    const float* W = (blockIdx.z == 0) ? W0 : (blockIdx.z == 1) ? W1
                   : (blockIdx.z == 2) ? W2 : W3;
    bf16_t*      T = (blockIdx.z == 0) ? T0 : (blockIdx.z == 1) ? T1
                   : (blockIdx.z == 2) ? T2 : T3;
    const int n0 = blockIdx.x * 32, k0 = blockIdx.y * 32;
    const int tx = threadIdx.x & 31, ty = threadIdx.x >> 5;   // ty 0..7
#pragma unroll
    for (int i = 0; i < 4; ++i)
        t[ty + i * 8][tx] = W[(size_t)(k0 + ty + i * 8) * 256 + n0 + tx];
    __syncthreads();
#pragma unroll
    for (int i = 0; i < 4; ++i)
        T[(size_t)(n0 + ty + i * 8) * 256 + k0 + tx] = (bf16_t)t[tx][ty + i * 8];
}

// ---------------------------------------------------------------------------
// MFMA GEMM (bf16 A): C[M,256] = A[M,256] @ BT[256,256]^T.
// ---------------------------------------------------------------------------
template<bool BIAS, bool OUT_BF16>
__global__ __launch_bounds__(256) void mfma_gemm(
    const bf16_t* __restrict__ A, const bf16_t* __restrict__ BT,
    const float* __restrict__ bias, void* __restrict__ Cout)
{
    const int wave = threadIdx.x >> 6;
    const int lane = threadIdx.x & 63;
    const int m0 = blockIdx.x * 16;
    const int n0 = wave * 64;
    const int lr = lane & 15;
    const int lk = (lane >> 4) * 8;

    const bf16_t* ap = A  + (size_t)(m0 + lr) * 256 + lk;
    const bf16_t* bp = BT + (size_t)(n0 + lr) * 256 + lk;

    f32x4 acc[4];
#pragma unroll
    for (int j = 0; j < 4; ++j) acc[j] = (f32x4)0.f;

#pragma unroll 2
    for (int k0 = 0; k0 < 256; k0 += 32) {
        bf16x8 a = *(const bf16x8*)(ap + k0);
#pragma unroll
        for (int j = 0; j < 4; ++j) {
            bf16x8 b = *(const bf16x8*)(bp + (size_t)j * 16 * 256 + k0);
            acc[j] = __builtin_amdgcn_mfma_f32_16x16x32_bf16(a, b, acc[j], 0, 0, 0);
        }
    }

    const int crow = m0 + (lane >> 4) * 4;
#pragma unroll
    for (int j = 0; j < 4; ++j) {
        const int col = n0 + j * 16 + lr;
        const float bv = BIAS ? bias[col] : 0.f;
#pragma unroll
        for (int r = 0; r < 4; ++r) {
            float val = acc[j][r] + bv;
            if (OUT_BF16)
                ((bf16_t*)Cout)[(size_t)(crow + r) * 256 + col] = (bf16_t)val;
            else
                ((float*)Cout)[(size_t)(crow + r) * 256 + col] = val;
        }
    }
}

// ---------------------------------------------------------------------------
// q-path GEMM, f32 A with in-register cvt, fused fixup epilogue.
// ---------------------------------------------------------------------------
__global__ __launch_bounds__(256) void mfma_gemm_q(
    const float* __restrict__ A, const bf16_t* __restrict__ BT,
    const float* __restrict__ qcpart, const float* __restrict__ attr,
    const float* __restrict__ Wq, float* __restrict__ Cout)
{
    const int wave = threadIdx.x >> 6;
    const int lane = threadIdx.x & 63;
    const int m0 = blockIdx.x * 16;
    const int n0 = wave * 64;
    const int lr = lane & 15;
    const int lk = (lane >> 4) * 8;

    const float*  ap = A  + (size_t)(m0 + lr) * 256 + lk;
    const bf16_t* bp = BT + (size_t)(n0 + lr) * 256 + lk;

    f32x4 acc[4];
#pragma unroll
    for (int j = 0; j < 4; ++j) acc[j] = (f32x4)0.f;

#pragma unroll 2
    for (int k0 = 0; k0 < 256; k0 += 32) {
        bf16x8 a = ldcvt8(ap + k0);
#pragma unroll
        for (int j = 0; j < 4; ++j) {
            bf16x8 b = *(const bf16x8*)(bp + (size_t)j * 16 * 256 + k0);
            acc[j] = __builtin_amdgcn_mfma_f32_16x16x32_bf16(a, b, acc[j], 0, 0, 0);
        }
    }

    const int crow = m0 + (lane >> 4) * 4;
#pragma unroll
    for (int j = 0; j < 4; ++j) {
        const int col = n0 + j * 16 + lr;
#pragma unroll
        for (int r = 0; r < 4; ++r) {
            const int row = crow + r;         // < 6400
            const int b = row / P_;
            float add = 0.f;
#pragma unroll
            for (int kc = 0; kc < 4; ++kc)
                add += qcpart[((size_t)kc * 64 + b) * EMB_ + col];
            add = fmaf(attr[(size_t)row * 4 + 0], Wq[(size_t)256 * EMB_ + col], add);
            add = fmaf(attr[(size_t)row * 4 + 1], Wq[(size_t)257 * EMB_ + col], add);
            add = fmaf(attr[(size_t)row * 4 + 2], Wq[(size_t)258 * EMB_ + col], add);
            add = fmaf(attr[(size_t)row * 4 + 3], Wq[(size_t)259 * EMB_ + col], add);
            Cout[(size_t)row * 256 + col] = acc[j][r] + add;
        }
    }
}

// ---------------------------------------------------------------------------
// Fused K+V projection + nodes cvt, v6 (R18): 4 m-tiles per wave, grid 1000,
// and the nbf store moved OUT of the k-loop (the per-iter `if (wave==0)`
// branch ended the scheduling region each iteration, blocking cross-iter
// load hoisting -- same poison as attn's rescale branch, R12). Post-loop,
// all 4 waves convert/store 4096 elems each, re-reading A from L2 (hot).
// ---------------------------------------------------------------------------
__global__ __launch_bounds__(256) void mfma_gemm_kv(
    const float* __restrict__ A, const bf16_t* __restrict__ BTk,
    const bf16_t* __restrict__ BTv,
    bf16_t* __restrict__ Ck, bf16_t* __restrict__ Cv,
    bf16_t* __restrict__ nbf)
{
    const int wave = threadIdx.x >> 6;
    const int lane = threadIdx.x & 63;
    const int m0 = blockIdx.x * 64;          // grid 1000 (64000 rows)
    const int n0 = wave * 64;
    const int lr = lane & 15;
    const int lk = (lane >> 4) * 8;

    const float* ap[4];
#pragma unroll
    for (int m = 0; m < 4; ++m)
        ap[m] = A + (size_t)(m0 + m * 16 + lr) * 256 + lk;
    const bf16_t* bpk = BTk + (size_t)(n0 + lr) * 256 + lk;
    const bf16_t* bpv = BTv + (size_t)(n0 + lr) * 256 + lk;

    f32x4 acck[4][4], accv[4][4];
#pragma unroll
    for (int m = 0; m < 4; ++m)
#pragma unroll
        for (int j = 0; j < 4; ++j) { acck[m][j] = (f32x4)0.f; accv[m][j] = (f32x4)0.f; }

    for (int k0 = 0; k0 < 256; k0 += 32) {   // branch-free body
        bf16x8 a0 = ldcvt8(ap[0] + k0);
        bf16x8 a1 = ldcvt8(ap[1] + k0);
        bf16x8 a2 = ldcvt8(ap[2] + k0);
        bf16x8 a3 = ldcvt8(ap[3] + k0);
#pragma unroll
        for (int j = 0; j < 4; ++j) {
            bf16x8 bk = *(const bf16x8*)(bpk + (size_t)j * 16 * 256 + k0);
            bf16x8 bv = *(const bf16x8*)(bpv + (size_t)j * 16 * 256 + k0);
            // swapped: lane holds C[m0+m*16+lr][n0+j*16+4*lg .. +3]
            acck[0][j] = __builtin_amdgcn_mfma_f32_16x16x32_bf16(bk, a0, acck[0][j], 0, 0, 0);
            acck[1][j] = __builtin_amdgcn_mfma_f32_16x16x32_bf16(bk, a1, acck[1][j], 0, 0, 0);
            acck[2][j] = __builtin_amdgcn_mfma_f32_16x16x32_bf16(bk, a2, acck[2][j], 0, 0, 0);
            acck[3][j] = __builtin_amdgcn_mfma_f32_16x16x32_bf16(bk, a3, acck[3][j], 0, 0, 0);
            accv[0][j] = __builtin_amdgcn_mfma_f32_16x16x32_bf16(bv, a0, accv[0][j], 0, 0, 0);
            accv[1][j] = __builtin_amdgcn_mfma_f32_16x16x32_bf16(bv, a1, accv[1][j], 0, 0, 0);
            accv[2][j] = __builtin_amdgcn_mfma_f32_16x16x32_bf16(bv, a2, accv[2][j], 0, 0, 0);
            accv[3][j] = __builtin_amdgcn_mfma_f32_16x16x32_bf16(bv, a3, accv[3][j], 0, 0, 0);
        }
    }

    // nbf production: 64 rows x 256 cols, 16384 bf16, split 4096/wave,
    // 8 x ldcvt8 per lane, re-reading A (L2-hot from the loop above).
    {
        const size_t base = (size_t)m0 * 256 + (size_t)wave * 4096 + (size_t)lane * 8;
#pragma unroll
        for (int i = 0; i < 8; ++i) {
            bf16x8 v = ldcvt8(A + base + (size_t)i * 512);
            *(bf16x8*)(nbf + base + (size_t)i * 512) = v;
        }
    }

    const int lg4 = (lane >> 4) * 4;
#pragma unroll
    for (int m = 0; m < 4; ++m) {
        const size_t rowoff = (size_t)(m0 + m * 16 + lr) * 256;
#pragma unroll
        for (int j = 0; j < 4; ++j) {
            const int col = n0 + j * 16 + lg4;
            bf16x4 ok, ov;
#pragma unroll
            for (int r = 0; r < 4; ++r) {
                ok[r] = (bf16_t)acck[m][j][r];
                ov[r] = (bf16_t)accv[m][j][r];
            }
            *(bf16x4*)(Ck + rowoff + col) = ok;
            *(bf16x4*)(Cv + rowoff + col) = ov;
        }
    }
}

// ---------------------------------------------------------------------------
// qc partials: qcpart[kc][b][n] = sum_{k in chunk kc} ctx[b][k]*Wq[260+k][n]
// ---------------------------------------------------------------------------
__global__ __launch_bounds__(256) void qc_kernel(
    const float* __restrict__ ctx, const float* __restrict__ Wq,
    float* __restrict__ qcpart)
{
    const int b = blockIdx.x;
    const int kc = blockIdx.y;
    const int tid = threadIdx.x;
    const float* c = ctx + (size_t)b * CTX_ + kc * 256;
    const float* w = Wq + (size_t)(260 + kc * 256) * EMB_ + tid;
    float acc = 0.f;
#pragma unroll 8
    for (int kk = 0; kk < 256; ++kk)
        acc = fmaf(c[kk], w[(size_t)kk * EMB_], acc);
    qcpart[((size_t)kc * 64 + b) * EMB_ + tid] = acc;
}

// ---------------------------------------------------------------------------
// MFMA flash attention (R11 structure, builtin PV MFMA; R18: s_setprio(1)
// around the MFMAs -- T5, independent barrier-free waves = m191's regime).
// Grid 448 x 1024 (16 waves = 16 heads).
// ---------------------------------------------------------------------------
struct AttnState { float m, l; f32x4 acc; };

template<bool TAIL>
__device__ __forceinline__ void attn_chunk(
    int n0, const bf16_t* __restrict__ kb, const bf16_t* __restrict__ vb,
    const float* __restrict__ maskrow, bf16x8 qfrag, int lr, int lg,
    AttnState& st)
{
    // K A-frag: row n = n0+lr, k(d) = 8*(lg&1)+i ; zero for lg>=2
    int nk = n0 + lr;
    if (TAIL) nk = (nk < N_) ? nk : (N_ - 1);
    bf16x8 ak = *(const bf16x8*)(kb + (size_t)nk * 256 + (lg & 1) * 8);
    if (lg >= 2) ak = (bf16x8)(bf16_t)0.0f;

    __builtin_amdgcn_s_setprio(1);
    f32x4 sc = __builtin_amdgcn_mfma_f32_16x16x32_bf16(ak, qfrag, (f32x4)0.f, 0, 0, 0);
    __builtin_amdgcn_s_setprio(0);

    // scores + mask (lane's 4 keys n = n0+4*lg+r, query p = lr)
    int nm = n0 + 4 * lg;
    if (TAIL) nm = (nm < 996) ? nm : 996;
    float4 mk = *(const float4*)&maskrow[nm];
    float s0 = fmaf(sc[0], 0.25f, mk.x);
    float s1 = fmaf(sc[1], 0.25f, mk.y);
    float s2 = fmaf(sc[2], 0.25f, mk.z);
    float s3 = fmaf(sc[3], 0.25f, mk.w);
    if (TAIL) {
        if (n0 + 4 * lg + 0 >= N_) s0 = -3.0e38f;
        if (n0 + 4 * lg + 1 >= N_) s1 = -3.0e38f;
        if (n0 + 4 * lg + 2 >= N_) s2 = -3.0e38f;
        if (n0 + 4 * lg + 3 >= N_) s3 = -3.0e38f;
    }

    // defer-max: common path is per-lane only (no cross-lane ops)
    float tmax = fmaxf(fmaxf(s0, s1), fmaxf(s2, s3));
    if (__any(tmax > st.m + 8.0f)) {        // rare (~once per state)
        float rmax = fmaxf(tmax, __shfl_xor(tmax, 16));
        rmax = fmaxf(rmax, __shfl_xor(rmax, 32));
        float mn = fmaxf(st.m, rmax);
        mfma_hazard_fence();                // no-op on builtin path
        float f = EXP2F((st.m - mn) * L2E); // first time: exp2(-inf)=0
        st.l *= f;
        st.acc *= f;
        st.m = mn;
    }
    float w0 = EXP2F((s0 - st.m) * L2E);    // bounded by e^8
    float w1 = EXP2F((s1 - st.m) * L2E);
    float w2 = EXP2F((s2 - st.m) * L2E);
    float w3 = EXP2F((s3 - st.m) * L2E);
    st.l += (w0 + w1) + (w2 + w3);
    bf16x4 pb;
    pb[0] = (bf16_t)w0; pb[1] = (bf16_t)w1; pb[2] = (bf16_t)w2; pb[3] = (bf16_t)w3;

    // V^T A-frag: row d = lr, k(n) = 4*lg+i  -> V[n0+4lg+i][d=lr]
    bf16x4 av;
#pragma unroll
    for (int i = 0; i < 4; ++i) {
        int nn = n0 + 4 * lg + i;
        if (TAIL) nn = (nn < N_) ? nn : (N_ - 1);   // w=0 kills contribution
        av[i] = vb[(size_t)nn * 256 + lr];
    }
    __builtin_amdgcn_s_setprio(1);
    pv_mfma16(av, pb, st.acc);
    __builtin_amdgcn_s_setprio(0);
}

__global__ __launch_bounds__(1024) void attn_mfma(
    const float* __restrict__ q, const bf16_t* __restrict__ k,
    const bf16_t* __restrict__ v, const float* __restrict__ mask,
    bf16_t* __restrict__ abuf)
{
    // XCD-bijective block mapping: 448 = 8 xcd * 56 slots; 56 = 8 b-groups * 7
    const int x = blockIdx.x;
    const int xcd = x & 7;
    const int slot = x >> 3;                 // 0..55
    const int b = xcd + 8 * (slot / 7);
    const int mtile = slot % 7;
    const int h = threadIdx.x >> 6;          // wave = head
    const int lane = threadIdx.x & 63;
    const int p0 = mtile * 16;
    const int lr = lane & 15;
    const int lg = lane >> 4;

    // Q B-frag (x32): col p = lr, k(d) = 8*lg+i ; zero for lg>=2
    const int pq = (p0 + lr < P_) ? (p0 + lr) : (P_ - 1);
    bf16x8 qfrag = (bf16x8)(bf16_t)0.0f;
    if (lg < 2) {
        const float* qp = q + ((size_t)b * P_ + pq) * 256 + h * 16 + lg * 8;
        float4 q0 = *(const float4*)qp;
        float4 q1 = *(const float4*)(qp + 4);
        qfrag[0] = (bf16_t)q0.x; qfrag[1] = (bf16_t)q0.y;
        qfrag[2] = (bf16_t)q0.z; qfrag[3] = (bf16_t)q0.w;
        qfrag[4] = (bf16_t)q1.x; qfrag[5] = (bf16_t)q1.y;
        qfrag[6] = (bf16_t)q1.z; qfrag[7] = (bf16_t)q1.w;
    }

    const bf16_t* kb = k + ((size_t)b * N_) * 256 + h * 16;
    const bf16_t* vb = v + ((size_t)b * N_) * 256 + h * 16;
    const float* maskrow = mask + ((size_t)b * P_ + pq) * N_;

    AttnState stA, stB;
    stA.m = -INFINITY; stA.l = 0.f; stA.acc = (f32x4)0.f;
    stB.m = -INFINITY; stB.l = 0.f; stB.acc = (f32x4)0.f;

    // 63 chunks: 30 pairs + chunks 960(A), 976(B), 992(A,tail)
    for (int n0 = 0; n0 < 960; n0 += 32) {
        attn_chunk<false>(n0,      kb, vb, maskrow, qfrag, lr, lg, stA);
        attn_chunk<false>(n0 + 16, kb, vb, maskrow, qfrag, lr, lg, stB);
    }
    attn_chunk<false>(960, kb, vb, maskrow, qfrag, lr, lg, stA);
    attn_chunk<false>(976, kb, vb, maskrow, qfrag, lr, lg, stB);
    attn_chunk<true>(992, kb, vb, maskrow, qfrag, lr, lg, stA);

    // merge the two states (flash combine)
    mfma_hazard_fence();                      // no-op on builtin path
    float mn = fmaxf(stA.m, stB.m);
    float fA = EXP2F((stA.m - mn) * L2E);
    float fB = EXP2F((stB.m - mn) * L2E);
    float l = stA.l * fA + stB.l * fB;
    f32x4 acc = stA.acc * fA + stB.acc * fB;

    // row sum of l across the 4 lanes sharing lr
    float L = l + __shfl_xor(l, 16);
    L += __shfl_xor(L, 32);

    if (p0 + lr < P_) {
        float inv = 1.0f / L;
        bf16x4 o;
        o[0] = (bf16_t)(acc[0] * inv);
        o[1] = (bf16_t)(acc[1] * inv);
        o[2] = (bf16_t)(acc[2] * inv);
        o[3] = (bf16_t)(acc[3] * inv);
        // out^T: lane holds out[p=lr][d=4*lg+r]
        *(bf16x4*)(abuf + ((size_t)b * P_ + p0 + lr) * 256 + h * 16 + 4 * lg) = o;
    }
}

// ---------------------------------------------------------------------------
// Fused pointer logits + row softmax (bf16 nodes operand). Grid 448 x 1024.
// ---------------------------------------------------------------------------
__global__ __launch_bounds__(1024) void logits_softmax(
    const bf16_t* __restrict__ mh, const bf16_t* __restrict__ nodes,
    const float* __restrict__ mask, float* __restrict__ out)
{
    __shared__ float redm[16][16];
    __shared__ float reds[16][16];

    // XCD-bijective: 448 = 8 xcd * 56; 56 = 8 b-groups * 7 mtiles
    const int x = blockIdx.x;
    const int xcd = x & 7;
    const int slot = x >> 3;                 // 0..55
    const int b = xcd + 8 * (slot / 7);
    const int mt = slot % 7;
    const int wave = threadIdx.x >> 6;       // ngrp 0..15
    const int lane = threadIdx.x & 63;
    const int p0 = mt * 16;
    const int n0 = wave * 64;
    const int lr = lane & 15;
    const int lg = lane >> 4;
    const int lk = lg * 8;

    const bf16_t* bbase = nodes + (size_t)b * N_ * 256;
    int nrow[4];
#pragma unroll
    for (int j = 0; j < 4; ++j) {
        int n = n0 + j * 16 + lr;
        nrow[j] = (n < N_) ? n : (N_ - 1);
    }
    const bf16_t* ap = mh + ((size_t)(b * P_) + p0 + lr) * 256 + lk;

    f32x4 acc[4];
#pragma unroll
    for (int j = 0; j < 4; ++j) acc[j] = (f32x4)0.f;

#pragma unroll 2
    for (int k0 = 0; k0 < 256; k0 += 32) {
        bf16x8 a = *(const bf16x8*)(ap + k0);
#pragma unroll
        for (int j = 0; j < 4; ++j) {
            bf16x8 bfr = *(const bf16x8*)(bbase + (size_t)nrow[j] * 256 + lk + k0);
            acc[j] = __builtin_amdgcn_mfma_f32_16x16x32_bf16(a, bfr, acc[j], 0, 0, 0);
        }
    }

    // logits: 10*tanh(s/16) + mask; invalid n -> -3e38 (excluded from softmax)
    const int prowb = p0 + lg * 4;
    float lv[4][4];
#pragma unroll
    for (int j = 0; j < 4; ++j) {
        const int n = n0 + j * 16 + lr;
        const int nc = (n < N_) ? n : (N_ - 1);
#pragma unroll
        for (int r = 0; r < 4; ++r) {
            const int p = prowb + r;
            const int pc = (p < P_) ? p : (P_ - 1);
            float xv = acc[j][r] * (1.0f / 16.0f);
            float e = EXP2F(xv * (2.0f * L2E));
            float t = 1.0f - 2.0f / (e + 1.0f);
            float val = 10.0f * t + mask[((size_t)(b * P_ + pc)) * N_ + nc];
            lv[j][r] = (n < N_) ? val : -3.0e38f;
        }
    }

    // row max: over j (in-thread), lr (shfl within 16-lane group), waves (LDS)
    float pm[4];
#pragma unroll
    for (int r = 0; r < 4; ++r) {
        pm[r] = fmaxf(fmaxf(lv[0][r], lv[1][r]), fmaxf(lv[2][r], lv[3][r]));
        pm[r] = fmaxf(pm[r], __shfl_xor(pm[r], 1));
        pm[r] = fmaxf(pm[r], __shfl_xor(pm[r], 2));
        pm[r] = fmaxf(pm[r], __shfl_xor(pm[r], 4));
        pm[r] = fmaxf(pm[r], __shfl_xor(pm[r], 8));
    }
    if (lr == 0) {
#pragma unroll
        for (int r = 0; r < 4; ++r) redm[wave][lg * 4 + r] = pm[r];
    }
    __syncthreads();
    float gm[4];
#pragma unroll
    for (int r = 0; r < 4; ++r) {
        float m_ = redm[0][lg * 4 + r];
#pragma unroll
        for (int w = 1; w < 16; ++w) m_ = fmaxf(m_, redm[w][lg * 4 + r]);
        gm[r] = m_;
    }

    // exp + row sum (same reduction path)
    float ps[4];
#pragma unroll
    for (int r = 0; r < 4; ++r) ps[r] = 0.f;
#pragma unroll
    for (int j = 0; j < 4; ++j)
#pragma unroll
        for (int r = 0; r < 4; ++r) {
            float e = EXP2F((lv[j][r] - gm[r]) * L2E);   // -3e38 -> 0
            lv[j][r] = e;
            ps[r] += e;
        }
#pragma unroll
    for (int r = 0; r < 4; ++r) {
        ps[r] += __shfl_xor(ps[r], 1);
        ps[r] += __shfl_xor(ps[r], 2);
        ps[r] += __shfl_xor(ps[r], 4);
        ps[r] += __shfl_xor(ps[r], 8);
    }
    if (lr == 0) {
#pragma unroll
        for (int r = 0; r < 4; ++r) reds[wave][lg * 4 + r] = ps[r];
    }
    __syncthreads();
    float inv[4];
#pragma unroll
    for (int r = 0; r < 4; ++r) {
        float s = 0.f;
#pragma unroll
        for (int w = 0; w < 16; ++w) s += reds[w][lg * 4 + r];
        inv[r] = 1.0f / s;
    }

    // normalized writes (each (b,p,n) exactly once)
#pragma unroll
    for (int j = 0; j < 4; ++j) {
        const int n = n0 + j * 16 + lr;
        if (n >= N_) continue;
#pragma unroll
        for (int r = 0; r < 4; ++r) {
            const int p = prowb + r;
            if (p >= P_) continue;
            out[((size_t)(b * P_ + p)) * N_ + n] = lv[j][r] * inv[r];
        }
    }
}

// ---------------------------------------------------------------------------
extern "C" void kernel_launch(void* const* d_in, const int* in_sizes, int n_in,
                              void* d_out, int out_size, void* d_ws, size_t ws_size,
                              hipStream_t stream)
{
    const float* lastnode = (const float*)d_in[0];   // [B,P,256]
    const float* attr     = (const float*)d_in[1];   // [B,P,4]
    const float* ctx      = (const float*)d_in[2];   // [B,1024]
    const float* mask     = (const float*)d_in[3];   // [B,P,N]
    const float* nodes    = (const float*)d_in[4];   // [B,N,256]
    const float* Wq       = (const float*)d_in[5];   // [1284,256]
    const float* Wk       = (const float*)d_in[6];   // [256,256]
    const float* Wv       = (const float*)d_in[7];   // [256,256]
    const float* Wcomb    = (const float*)d_in[8];   // [256,256]
    const float* bcomb    = (const float*)d_in[9];   // [256]
    float* out = (float*)d_out;

    // Workspace layout (offsets in floats). Total 27,230,208 f = 108.9 MB.
    float* ws = (float*)d_ws;
    bf16_t* kbuf   = (bf16_t*)(ws);                   // 16,384,000 bf16
    bf16_t* vbuf   = (bf16_t*)(ws + 8192000);         // 16,384,000 bf16
    float*  qbuf   = ws + 16384000;                   // 1,638,400 f
    bf16_t* nbf    = (bf16_t*)(ws + 18022400);        // 16,384,000 bf16
    bf16_t* WkT    = (bf16_t*)(ws + 26214400);        // 65,536 bf16
    bf16_t* WvT    = (bf16_t*)(ws + 26247168);        // 65,536 bf16
    bf16_t* WcombT = (bf16_t*)(ws + 26279936);        // 65,536 bf16
    bf16_t* WqmT   = (bf16_t*)(ws + 26312704);        // 65,536 bf16
    float*  qcpart = ws + 26345472;                   // 65,536 f (4x64x256)
    bf16_t* abuf   = (bf16_t*)(ws + 26411008);        // 1,638,400 bf16
    // Overlay: mhbuf reuses kbuf (K dead after attn_mfma); logits reads rows
    // up to b*100+111 -> slack is inside kbuf's 64000 rows.
    bf16_t* mhbuf = kbuf;

    // 1) weight transposes -> bf16 (Wk, Wv, Wcomb, Wq[0:256))
    wtrans_kernel<<<dim3(8, 8, 4), 256, 0, stream>>>(
        Wk, Wv, Wcomb, Wq, WkT, WvT, WcombT, WqmT);

    // 2) q pipeline: ctx partials + fused GEMM/fixup (f32 A, in-register cvt)
    qc_kernel<<<dim3(64, 4), 256, 0, stream>>>(ctx, Wq, qcpart);
    mfma_gemm_q<<<400, 256, 0, stream>>>(lastnode, WqmT, qcpart, attr, Wq, qbuf);

    // 3) fused k+v projection + nodes cvt, 4 m-tiles/wave, branch-free loop
    mfma_gemm_kv<<<1000, 256, 0, stream>>>(nodes, WkT, WvT, kbuf, vbuf, nbf);

    // 4) fused MFMA flash attention (builtin PV MFMA, setprio) -> abuf
    attn_mfma<<<448, 1024, 0, stream>>>(qbuf, kbuf, vbuf, mask, abuf);

    // 5) combine projection (MFMA, bias, bf16 out into mhbuf)
    mfma_gemm<true, true><<<400, 256, 0, stream>>>(abuf, WcombT, bcomb, mhbuf);

    // 6) fused pointer logits + softmax (bf16 nodes from nbf) -> out
    logits_softmax<<<448, 1024, 0, stream>>>(mhbuf, nbf, mask, out);
}

// Round 20
// 277.046 us; speedup vs baseline: 1.0421x; 1.0421x over previous
//
#include <hip/hip_runtime.h>
#include <hip/hip_bf16.h>
#include <math.h>

// Problem constants (from reference)
#define B_  64
#define P_  100
#define N_  1000
#define EMB_ 256
#define H_  16
#define D_  16
#define CTX_ 1024
#define L2E 1.44269504088896340736f

#if __has_builtin(__builtin_amdgcn_exp2f)
#define EXP2F(x) __builtin_amdgcn_exp2f(x)
#else
#define EXP2F(x) exp2f(x)
#endif

typedef __bf16 bf16_t;
typedef bf16_t bf16x8 __attribute__((ext_vector_type(8)));
typedef bf16_t bf16x4 __attribute__((ext_vector_type(4)));
typedef float  f32x4  __attribute__((ext_vector_type(4)));
typedef short  s16x4  __attribute__((ext_vector_type(4)));

// PV MFMA via builtin when available (R16-proven correct/neutral);
// asm fallback with manual hazard fences otherwise.
#if __has_builtin(__builtin_amdgcn_mfma_f32_16x16x16bf16_1k)
__device__ __forceinline__ void pv_mfma16(bf16x4 a, bf16x4 b, f32x4& c)
{
    s16x4 ai, bi;
    __builtin_memcpy(&ai, &a, 8);
    __builtin_memcpy(&bi, &b, 8);
    c = __builtin_amdgcn_mfma_f32_16x16x16bf16_1k(ai, bi, c, 0, 0, 0);
}
__device__ __forceinline__ void mfma_hazard_fence() {}
#else
__device__ __forceinline__ void pv_mfma16(bf16x4 a, bf16x4 b, f32x4& c)
{
    asm("s_nop 1\n\tv_mfma_f32_16x16x16_bf16 %0, %1, %2, %0"
        : "+v"(c) : "v"(a), "v"(b));
}
__device__ __forceinline__ void mfma_hazard_fence()
{
    __builtin_amdgcn_sched_barrier(0);
    asm volatile("s_nop 7\n\ts_nop 3");
}
#endif

// Load 8 consecutive f32 and convert to bf16x8 in-register.
__device__ __forceinline__ bf16x8 ldcvt8(const float* __restrict__ p)
{
    float4 u = *(const float4*)p;
    float4 v = *(const float4*)(p + 4);
    bf16x8 r;
    r[0] = (bf16_t)u.x; r[1] = (bf16_t)u.y; r[2] = (bf16_t)u.z; r[3] = (bf16_t)u.w;
    r[4] = (bf16_t)v.x; r[5] = (bf16_t)v.y; r[6] = (bf16_t)v.z; r[7] = (bf16_t)v.w;
    return r;
}

// ---------------------------------------------------------------------------
// Transpose four 256x256 f32 weights -> bf16 WT[n][k]
// ---------------------------------------------------------------------------
__global__ __launch_bounds__(256) void wtrans_kernel(
    const float* __restrict__ W0, const float* __restrict__ W1,
    const float* __restrict__ W2, const float* __restrict__ W3,
    bf16_t* __restrict__ T0, bf16_t* __restrict__ T1,
    bf16_t* __restrict__ T2, bf16_t* __restrict__ T3)
{
    __shared__ float t[32][33];
    const float* W = (blockIdx.z == 0) ? W0 : (blockIdx.z == 1) ? W1
                   : (blockIdx.z == 2) ? W2 : W3;
    bf16_t*      T = (blockIdx.z == 0) ? T0 : (blockIdx.z == 1) ? T1
                   : (blockIdx.z == 2) ? T2 : T3;
    const int n0 = blockIdx.x * 32, k0 = blockIdx.y * 32;
    const int tx = threadIdx.x & 31, ty = threadIdx.x >> 5;   // ty 0..7
#pragma unroll
    for (int i = 0; i < 4; ++i)
        t[ty + i * 8][tx] = W[(size_t)(k0 + ty + i * 8) * 256 + n0 + tx];
    __syncthreads();
#pragma unroll
    for (int i = 0; i < 4; ++i)
        T[(size_t)(n0 + ty + i * 8) * 256 + k0 + tx] = (bf16_t)t[tx][ty + i * 8];
}

// ---------------------------------------------------------------------------
// MFMA GEMM (bf16 A): C[M,256] = A[M,256] @ BT[256,256]^T.
// ---------------------------------------------------------------------------
template<bool BIAS, bool OUT_BF16>
__global__ __launch_bounds__(256) void mfma_gemm(
    const bf16_t* __restrict__ A, const bf16_t* __restrict__ BT,
    const float* __restrict__ bias, void* __restrict__ Cout)
{
    const int wave = threadIdx.x >> 6;
    const int lane = threadIdx.x & 63;
    const int m0 = blockIdx.x * 16;
    const int n0 = wave * 64;
    const int lr = lane & 15;
    const int lk = (lane >> 4) * 8;

    const bf16_t* ap = A  + (size_t)(m0 + lr) * 256 + lk;
    const bf16_t* bp = BT + (size_t)(n0 + lr) * 256 + lk;

    f32x4 acc[4];
#pragma unroll
    for (int j = 0; j < 4; ++j) acc[j] = (f32x4)0.f;

#pragma unroll 2
    for (int k0 = 0; k0 < 256; k0 += 32) {
        bf16x8 a = *(const bf16x8*)(ap + k0);
#pragma unroll
        for (int j = 0; j < 4; ++j) {
            bf16x8 b = *(const bf16x8*)(bp + (size_t)j * 16 * 256 + k0);
            acc[j] = __builtin_amdgcn_mfma_f32_16x16x32_bf16(a, b, acc[j], 0, 0, 0);
        }
    }

    const int crow = m0 + (lane >> 4) * 4;
#pragma unroll
    for (int j = 0; j < 4; ++j) {
        const int col = n0 + j * 16 + lr;
        const float bv = BIAS ? bias[col] : 0.f;
#pragma unroll
        for (int r = 0; r < 4; ++r) {
            float val = acc[j][r] + bv;
            if (OUT_BF16)
                ((bf16_t*)Cout)[(size_t)(crow + r) * 256 + col] = (bf16_t)val;
            else
                ((float*)Cout)[(size_t)(crow + r) * 256 + col] = val;
        }
    }
}

// ---------------------------------------------------------------------------
// q-path GEMM, f32 A with in-register cvt, fused fixup epilogue.
// ---------------------------------------------------------------------------
__global__ __launch_bounds__(256) void mfma_gemm_q(
    const float* __restrict__ A, const bf16_t* __restrict__ BT,
    const float* __restrict__ qcpart, const float* __restrict__ attr,
    const float* __restrict__ Wq, float* __restrict__ Cout)
{
    const int wave = threadIdx.x >> 6;
    const int lane = threadIdx.x & 63;
    const int m0 = blockIdx.x * 16;
    const int n0 = wave * 64;
    const int lr = lane & 15;
    const int lk = (lane >> 4) * 8;

    const float*  ap = A  + (size_t)(m0 + lr) * 256 + lk;
    const bf16_t* bp = BT + (size_t)(n0 + lr) * 256 + lk;

    f32x4 acc[4];
#pragma unroll
    for (int j = 0; j < 4; ++j) acc[j] = (f32x4)0.f;

#pragma unroll 2
    for (int k0 = 0; k0 < 256; k0 += 32) {
        bf16x8 a = ldcvt8(ap + k0);
#pragma unroll
        for (int j = 0; j < 4; ++j) {
            bf16x8 b = *(const bf16x8*)(bp + (size_t)j * 16 * 256 + k0);
            acc[j] = __builtin_amdgcn_mfma_f32_16x16x32_bf16(a, b, acc[j], 0, 0, 0);
        }
    }

    const int crow = m0 + (lane >> 4) * 4;
#pragma unroll
    for (int j = 0; j < 4; ++j) {
        const int col = n0 + j * 16 + lr;
#pragma unroll
        for (int r = 0; r < 4; ++r) {
            const int row = crow + r;         // < 6400
            const int b = row / P_;
            float add = 0.f;
#pragma unroll
            for (int kc = 0; kc < 4; ++kc)
                add += qcpart[((size_t)kc * 64 + b) * EMB_ + col];
            add = fmaf(attr[(size_t)row * 4 + 0], Wq[(size_t)256 * EMB_ + col], add);
            add = fmaf(attr[(size_t)row * 4 + 1], Wq[(size_t)257 * EMB_ + col], add);
            add = fmaf(attr[(size_t)row * 4 + 2], Wq[(size_t)258 * EMB_ + col], add);
            add = fmaf(attr[(size_t)row * 4 + 3], Wq[(size_t)259 * EMB_ + col], add);
            Cout[(size_t)row * 256 + col] = acc[j][r] + add;
        }
    }
}

// ---------------------------------------------------------------------------
// Fused K+V projection + nodes cvt (R17-proven): 4 m-tiles per wave, grid
// 1000; wave 0 stores nbf inside the k-loop (R18's branch-free/post-loop
// variant REGRESSED: occupancy 10.5%, +20 us -- reverted).
// Swapped-operand MFMA -> coalesced bf16x4 stores.
// ---------------------------------------------------------------------------
__global__ __launch_bounds__(256) void mfma_gemm_kv(
    const float* __restrict__ A, const bf16_t* __restrict__ BTk,
    const bf16_t* __restrict__ BTv,
    bf16_t* __restrict__ Ck, bf16_t* __restrict__ Cv,
    bf16_t* __restrict__ nbf)
{
    const int wave = threadIdx.x >> 6;
    const int lane = threadIdx.x & 63;
    const int m0 = blockIdx.x * 64;          // grid 1000 (64000 rows)
    const int n0 = wave * 64;
    const int lr = lane & 15;
    const int lk = (lane >> 4) * 8;

    const float* ap[4];
    bf16_t* np[4];
#pragma unroll
    for (int m = 0; m < 4; ++m) {
        ap[m] = A   + (size_t)(m0 + m * 16 + lr) * 256 + lk;
        np[m] = nbf + (size_t)(m0 + m * 16 + lr) * 256 + lk;
    }
    const bf16_t* bpk = BTk + (size_t)(n0 + lr) * 256 + lk;
    const bf16_t* bpv = BTv + (size_t)(n0 + lr) * 256 + lk;

    f32x4 acck[4][4], accv[4][4];
#pragma unroll
    for (int m = 0; m < 4; ++m)
#pragma unroll
        for (int j = 0; j < 4; ++j) { acck[m][j] = (f32x4)0.f; accv[m][j] = (f32x4)0.f; }

    for (int k0 = 0; k0 < 256; k0 += 32) {
        bf16x8 a0 = ldcvt8(ap[0] + k0);
        bf16x8 a1 = ldcvt8(ap[1] + k0);
        bf16x8 a2 = ldcvt8(ap[2] + k0);
        bf16x8 a3 = ldcvt8(ap[3] + k0);
        if (wave == 0) {                      // fused nodes->bf16 store
            *(bf16x8*)(np[0] + k0) = a0;
            *(bf16x8*)(np[1] + k0) = a1;
            *(bf16x8*)(np[2] + k0) = a2;
            *(bf16x8*)(np[3] + k0) = a3;
        }
#pragma unroll
        for (int j = 0; j < 4; ++j) {
            bf16x8 bk = *(const bf16x8*)(bpk + (size_t)j * 16 * 256 + k0);
            bf16x8 bv = *(const bf16x8*)(bpv + (size_t)j * 16 * 256 + k0);
            // swapped: lane holds C[m0+m*16+lr][n0+j*16+4*lg .. +3]
            acck[0][j] = __builtin_amdgcn_mfma_f32_16x16x32_bf16(bk, a0, acck[0][j], 0, 0, 0);
            acck[1][j] = __builtin_amdgcn_mfma_f32_16x16x32_bf16(bk, a1, acck[1][j], 0, 0, 0);
            acck[2][j] = __builtin_amdgcn_mfma_f32_16x16x32_bf16(bk, a2, acck[2][j], 0, 0, 0);
            acck[3][j] = __builtin_amdgcn_mfma_f32_16x16x32_bf16(bk, a3, acck[3][j], 0, 0, 0);
            accv[0][j] = __builtin_amdgcn_mfma_f32_16x16x32_bf16(bv, a0, accv[0][j], 0, 0, 0);
            accv[1][j] = __builtin_amdgcn_mfma_f32_16x16x32_bf16(bv, a1, accv[1][j], 0, 0, 0);
            accv[2][j] = __builtin_amdgcn_mfma_f32_16x16x32_bf16(bv, a2, accv[2][j], 0, 0, 0);
            accv[3][j] = __builtin_amdgcn_mfma_f32_16x16x32_bf16(bv, a3, accv[3][j], 0, 0, 0);
        }
    }

    const int lg4 = (lane >> 4) * 4;
#pragma unroll
    for (int m = 0; m < 4; ++m) {
        const size_t rowoff = (size_t)(m0 + m * 16 + lr) * 256;
#pragma unroll
        for (int j = 0; j < 4; ++j) {
            const int col = n0 + j * 16 + lg4;
            bf16x4 ok, ov;
#pragma unroll
            for (int r = 0; r < 4; ++r) {
                ok[r] = (bf16_t)acck[m][j][r];
                ov[r] = (bf16_t)accv[m][j][r];
            }
            *(bf16x4*)(Ck + rowoff + col) = ok;
            *(bf16x4*)(Cv + rowoff + col) = ov;
        }
    }
}

// ---------------------------------------------------------------------------
// qc partials: qcpart[kc][b][n] = sum_{k in chunk kc} ctx[b][k]*Wq[260+k][n]
// ---------------------------------------------------------------------------
__global__ __launch_bounds__(256) void qc_kernel(
    const float* __restrict__ ctx, const float* __restrict__ Wq,
    float* __restrict__ qcpart)
{
    const int b = blockIdx.x;
    const int kc = blockIdx.y;
    const int tid = threadIdx.x;
    const float* c = ctx + (size_t)b * CTX_ + kc * 256;
    const float* w = Wq + (size_t)(260 + kc * 256) * EMB_ + tid;
    float acc = 0.f;
#pragma unroll 8
    for (int kk = 0; kk < 256; ++kk)
        acc = fmaf(c[kk], w[(size_t)kk * EMB_], acc);
    qcpart[((size_t)kc * 64 + b) * EMB_ + tid] = acc;
}

// ---------------------------------------------------------------------------
// MFMA flash attention (R11 structure, builtin PV MFMA; NO setprio --
// R18 showed it is neutral-to-negative here). Grid 448 x 1024.
// ---------------------------------------------------------------------------
struct AttnState { float m, l; f32x4 acc; };

template<bool TAIL>
__device__ __forceinline__ void attn_chunk(
    int n0, const bf16_t* __restrict__ kb, const bf16_t* __restrict__ vb,
    const float* __restrict__ maskrow, bf16x8 qfrag, int lr, int lg,
    AttnState& st)
{
    // K A-frag: row n = n0+lr, k(d) = 8*(lg&1)+i ; zero for lg>=2
    int nk = n0 + lr;
    if (TAIL) nk = (nk < N_) ? nk : (N_ - 1);
    bf16x8 ak = *(const bf16x8*)(kb + (size_t)nk * 256 + (lg & 1) * 8);
    if (lg >= 2) ak = (bf16x8)(bf16_t)0.0f;

    f32x4 sc = __builtin_amdgcn_mfma_f32_16x16x32_bf16(ak, qfrag, (f32x4)0.f, 0, 0, 0);

    // scores + mask (lane's 4 keys n = n0+4*lg+r, query p = lr)
    int nm = n0 + 4 * lg;
    if (TAIL) nm = (nm < 996) ? nm : 996;
    float4 mk = *(const float4*)&maskrow[nm];
    float s0 = fmaf(sc[0], 0.25f, mk.x);
    float s1 = fmaf(sc[1], 0.25f, mk.y);
    float s2 = fmaf(sc[2], 0.25f, mk.z);
    float s3 = fmaf(sc[3], 0.25f, mk.w);
    if (TAIL) {
        if (n0 + 4 * lg + 0 >= N_) s0 = -3.0e38f;
        if (n0 + 4 * lg + 1 >= N_) s1 = -3.0e38f;
        if (n0 + 4 * lg + 2 >= N_) s2 = -3.0e38f;
        if (n0 + 4 * lg + 3 >= N_) s3 = -3.0e38f;
    }

    // defer-max: common path is per-lane only (no cross-lane ops)
    float tmax = fmaxf(fmaxf(s0, s1), fmaxf(s2, s3));
    if (__any(tmax > st.m + 8.0f)) {        // rare (~once per state)
        float rmax = fmaxf(tmax, __shfl_xor(tmax, 16));
        rmax = fmaxf(rmax, __shfl_xor(rmax, 32));
        float mn = fmaxf(st.m, rmax);
        mfma_hazard_fence();                // no-op on builtin path
        float f = EXP2F((st.m - mn) * L2E); // first time: exp2(-inf)=0
        st.l *= f;
        st.acc *= f;
        st.m = mn;
    }
    float w0 = EXP2F((s0 - st.m) * L2E);    // bounded by e^8
    float w1 = EXP2F((s1 - st.m) * L2E);
    float w2 = EXP2F((s2 - st.m) * L2E);
    float w3 = EXP2F((s3 - st.m) * L2E);
    st.l += (w0 + w1) + (w2 + w3);
    bf16x4 pb;
    pb[0] = (bf16_t)w0; pb[1] = (bf16_t)w1; pb[2] = (bf16_t)w2; pb[3] = (bf16_t)w3;

    // V^T A-frag: row d = lr, k(n) = 4*lg+i  -> V[n0+4lg+i][d=lr]
    bf16x4 av;
#pragma unroll
    for (int i = 0; i < 4; ++i) {
        int nn = n0 + 4 * lg + i;
        if (TAIL) nn = (nn < N_) ? nn : (N_ - 1);   // w=0 kills contribution
        av[i] = vb[(size_t)nn * 256 + lr];
    }
    pv_mfma16(av, pb, st.acc);
}

__global__ __launch_bounds__(1024) void attn_mfma(
    const float* __restrict__ q, const bf16_t* __restrict__ k,
    const bf16_t* __restrict__ v, const float* __restrict__ mask,
    bf16_t* __restrict__ abuf)
{
    // XCD-bijective block mapping: 448 = 8 xcd * 56 slots; 56 = 8 b-groups * 7
    const int x = blockIdx.x;
    const int xcd = x & 7;
    const int slot = x >> 3;                 // 0..55
    const int b = xcd + 8 * (slot / 7);
    const int mtile = slot % 7;
    const int h = threadIdx.x >> 6;          // wave = head
    const int lane = threadIdx.x & 63;
    const int p0 = mtile * 16;
    const int lr = lane & 15;
    const int lg = lane >> 4;

    // Q B-frag (x32): col p = lr, k(d) = 8*lg+i ; zero for lg>=2
    const int pq = (p0 + lr < P_) ? (p0 + lr) : (P_ - 1);
    bf16x8 qfrag = (bf16x8)(bf16_t)0.0f;
    if (lg < 2) {
        const float* qp = q + ((size_t)b * P_ + pq) * 256 + h * 16 + lg * 8;
        float4 q0 = *(const float4*)qp;
        float4 q1 = *(const float4*)(qp + 4);
        qfrag[0] = (bf16_t)q0.x; qfrag[1] = (bf16_t)q0.y;
        qfrag[2] = (bf16_t)q0.z; qfrag[3] = (bf16_t)q0.w;
        qfrag[4] = (bf16_t)q1.x; qfrag[5] = (bf16_t)q1.y;
        qfrag[6] = (bf16_t)q1.z; qfrag[7] = (bf16_t)q1.w;
    }

    const bf16_t* kb = k + ((size_t)b * N_) * 256 + h * 16;
    const bf16_t* vb = v + ((size_t)b * N_) * 256 + h * 16;
    const float* maskrow = mask + ((size_t)b * P_ + pq) * N_;

    AttnState stA, stB;
    stA.m = -INFINITY; stA.l = 0.f; stA.acc = (f32x4)0.f;
    stB.m = -INFINITY; stB.l = 0.f; stB.acc = (f32x4)0.f;

    // 63 chunks: 30 pairs + chunks 960(A), 976(B), 992(A,tail)
    for (int n0 = 0; n0 < 960; n0 += 32) {
        attn_chunk<false>(n0,      kb, vb, maskrow, qfrag, lr, lg, stA);
        attn_chunk<false>(n0 + 16, kb, vb, maskrow, qfrag, lr, lg, stB);
    }
    attn_chunk<false>(960, kb, vb, maskrow, qfrag, lr, lg, stA);
    attn_chunk<false>(976, kb, vb, maskrow, qfrag, lr, lg, stB);
    attn_chunk<true>(992, kb, vb, maskrow, qfrag, lr, lg, stA);

    // merge the two states (flash combine)
    mfma_hazard_fence();                      // no-op on builtin path
    float mn = fmaxf(stA.m, stB.m);
    float fA = EXP2F((stA.m - mn) * L2E);
    float fB = EXP2F((stB.m - mn) * L2E);
    float l = stA.l * fA + stB.l * fB;
    f32x4 acc = stA.acc * fA + stB.acc * fB;

    // row sum of l across the 4 lanes sharing lr
    float L = l + __shfl_xor(l, 16);
    L += __shfl_xor(L, 32);

    if (p0 + lr < P_) {
        float inv = 1.0f / L;
        bf16x4 o;
        o[0] = (bf16_t)(acc[0] * inv);
        o[1] = (bf16_t)(acc[1] * inv);
        o[2] = (bf16_t)(acc[2] * inv);
        o[3] = (bf16_t)(acc[3] * inv);
        // out^T: lane holds out[p=lr][d=4*lg+r]
        *(bf16x4*)(abuf + ((size_t)b * P_ + p0 + lr) * 256 + h * 16 + 4 * lg) = o;
    }
}

// ---------------------------------------------------------------------------
// Fused pointer logits + row softmax (bf16 nodes operand). Grid 448 x 1024.
// ---------------------------------------------------------------------------
__global__ __launch_bounds__(1024) void logits_softmax(
    const bf16_t* __restrict__ mh, const bf16_t* __restrict__ nodes,
    const float* __restrict__ mask, float* __restrict__ out)
{
    __shared__ float redm[16][16];
    __shared__ float reds[16][16];

    // XCD-bijective: 448 = 8 xcd * 56; 56 = 8 b-groups * 7 mtiles
    const int x = blockIdx.x;
    const int xcd = x & 7;
    const int slot = x >> 3;                 // 0..55
    const int b = xcd + 8 * (slot / 7);
    const int mt = slot % 7;
    const int wave = threadIdx.x >> 6;       // ngrp 0..15
    const int lane = threadIdx.x & 63;
    const int p0 = mt * 16;
    const int n0 = wave * 64;
    const int lr = lane & 15;
    const int lg = lane >> 4;
    const int lk = lg * 8;

    const bf16_t* bbase = nodes + (size_t)b * N_ * 256;
    int nrow[4];
#pragma unroll
    for (int j = 0; j < 4; ++j) {
        int n = n0 + j * 16 + lr;
        nrow[j] = (n < N_) ? n : (N_ - 1);
    }
    const bf16_t* ap = mh + ((size_t)(b * P_) + p0 + lr) * 256 + lk;

    f32x4 acc[4];
#pragma unroll
    for (int j = 0; j < 4; ++j) acc[j] = (f32x4)0.f;

#pragma unroll 2
    for (int k0 = 0; k0 < 256; k0 += 32) {
        bf16x8 a = *(const bf16x8*)(ap + k0);
#pragma unroll
        for (int j = 0; j < 4; ++j) {
            bf16x8 bfr = *(const bf16x8*)(bbase + (size_t)nrow[j] * 256 + lk + k0);
            acc[j] = __builtin_amdgcn_mfma_f32_16x16x32_bf16(a, bfr, acc[j], 0, 0, 0);
        }
    }

    // logits: 10*tanh(s/16) + mask; invalid n -> -3e38 (excluded from softmax)
    const int prowb = p0 + lg * 4;
    float lv[4][4];
#pragma unroll
    for (int j = 0; j < 4; ++j) {
        const int n = n0 + j * 16 + lr;
        const int nc = (n < N_) ? n : (N_ - 1);
#pragma unroll
        for (int r = 0; r < 4; ++r) {
            const int p = prowb + r;
            const int pc = (p < P_) ? p : (P_ - 1);
            float xv = acc[j][r] * (1.0f / 16.0f);
            float e = EXP2F(xv * (2.0f * L2E));
            float t = 1.0f - 2.0f / (e + 1.0f);
            float val = 10.0f * t + mask[((size_t)(b * P_ + pc)) * N_ + nc];
            lv[j][r] = (n < N_) ? val : -3.0e38f;
        }
    }

    // row max: over j (in-thread), lr (shfl within 16-lane group), waves (LDS)
    float pm[4];
#pragma unroll
    for (int r = 0; r < 4; ++r) {
        pm[r] = fmaxf(fmaxf(lv[0][r], lv[1][r]), fmaxf(lv[2][r], lv[3][r]));
        pm[r] = fmaxf(pm[r], __shfl_xor(pm[r], 1));
        pm[r] = fmaxf(pm[r], __shfl_xor(pm[r], 2));
        pm[r] = fmaxf(pm[r], __shfl_xor(pm[r], 4));
        pm[r] = fmaxf(pm[r], __shfl_xor(pm[r], 8));
    }
    if (lr == 0) {
#pragma unroll
        for (int r = 0; r < 4; ++r) redm[wave][lg * 4 + r] = pm[r];
    }
    __syncthreads();
    float gm[4];
#pragma unroll
    for (int r = 0; r < 4; ++r) {
        float m_ = redm[0][lg * 4 + r];
#pragma unroll
        for (int w = 1; w < 16; ++w) m_ = fmaxf(m_, redm[w][lg * 4 + r]);
        gm[r] = m_;
    }

    // exp + row sum (same reduction path)
    float ps[4];
#pragma unroll
    for (int r = 0; r < 4; ++r) ps[r] = 0.f;
#pragma unroll
    for (int j = 0; j < 4; ++j)
#pragma unroll
        for (int r = 0; r < 4; ++r) {
            float e = EXP2F((lv[j][r] - gm[r]) * L2E);   // -3e38 -> 0
            lv[j][r] = e;
            ps[r] += e;
        }
#pragma unroll
    for (int r = 0; r < 4; ++r) {
        ps[r] += __shfl_xor(ps[r], 1);
        ps[r] += __shfl_xor(ps[r], 2);
        ps[r] += __shfl_xor(ps[r], 4);
        ps[r] += __shfl_xor(ps[r], 8);
    }
    if (lr == 0) {
#pragma unroll
        for (int r = 0; r < 4; ++r) reds[wave][lg * 4 + r] = ps[r];
    }
    __syncthreads();
    float inv[4];
#pragma unroll
    for (int r = 0; r < 4; ++r) {
        float s = 0.f;
#pragma unroll
        for (int w = 0; w < 16; ++w) s += reds[w][lg * 4 + r];
        inv[r] = 1.0f / s;
    }

    // normalized writes (each (b,p,n) exactly once)
#pragma unroll
    for (int j = 0; j < 4; ++j) {
        const int n = n0 + j * 16 + lr;
        if (n >= N_) continue;
#pragma unroll
        for (int r = 0; r < 4; ++r) {
            const int p = prowb + r;
            if (p >= P_) continue;
            out[((size_t)(b * P_ + p)) * N_ + n] = lv[j][r] * inv[r];
        }
    }
}

// ---------------------------------------------------------------------------
extern "C" void kernel_launch(void* const* d_in, const int* in_sizes, int n_in,
                              void* d_out, int out_size, void* d_ws, size_t ws_size,
                              hipStream_t stream)
{
    const float* lastnode = (const float*)d_in[0];   // [B,P,256]
    const float* attr     = (const float*)d_in[1];   // [B,P,4]
    const float* ctx      = (const float*)d_in[2];   // [B,1024]
    const float* mask     = (const float*)d_in[3];   // [B,P,N]
    const float* nodes    = (const float*)d_in[4];   // [B,N,256]
    const float* Wq       = (const float*)d_in[5];   // [1284,256]
    const float* Wk       = (const float*)d_in[6];   // [256,256]
    const float* Wv       = (const float*)d_in[7];   // [256,256]
    const float* Wcomb    = (const float*)d_in[8];   // [256,256]
    const float* bcomb    = (const float*)d_in[9];   // [256]
    float* out = (float*)d_out;

    // Workspace layout (offsets in floats). Total 27,230,208 f = 108.9 MB.
    float* ws = (float*)d_ws;
    bf16_t* kbuf   = (bf16_t*)(ws);                   // 16,384,000 bf16
    bf16_t* vbuf   = (bf16_t*)(ws + 8192000);         // 16,384,000 bf16
    float*  qbuf   = ws + 16384000;                   // 1,638,400 f
    bf16_t* nbf    = (bf16_t*)(ws + 18022400);        // 16,384,000 bf16
    bf16_t* WkT    = (bf16_t*)(ws + 26214400);        // 65,536 bf16
    bf16_t* WvT    = (bf16_t*)(ws + 26247168);        // 65,536 bf16
    bf16_t* WcombT = (bf16_t*)(ws + 26279936);        // 65,536 bf16
    bf16_t* WqmT   = (bf16_t*)(ws + 26312704);        // 65,536 bf16
    float*  qcpart = ws + 26345472;                   // 65,536 f (4x64x256)
    bf16_t* abuf   = (bf16_t*)(ws + 26411008);        // 1,638,400 bf16
    // Overlay: mhbuf reuses kbuf (K dead after attn_mfma); logits reads rows
    // up to b*100+111 -> slack is inside kbuf's 64000 rows.
    bf16_t* mhbuf = kbuf;

    // 1) weight transposes -> bf16 (Wk, Wv, Wcomb, Wq[0:256))
    wtrans_kernel<<<dim3(8, 8, 4), 256, 0, stream>>>(
        Wk, Wv, Wcomb, Wq, WkT, WvT, WcombT, WqmT);

    // 2) q pipeline: ctx partials + fused GEMM/fixup (f32 A, in-register cvt)
    qc_kernel<<<dim3(64, 4), 256, 0, stream>>>(ctx, Wq, qcpart);
    mfma_gemm_q<<<400, 256, 0, stream>>>(lastnode, WqmT, qcpart, attr, Wq, qbuf);

    // 3) fused k+v projection + nodes cvt, 4 m-tiles/wave (grid 1000)
    mfma_gemm_kv<<<1000, 256, 0, stream>>>(nodes, WkT, WvT, kbuf, vbuf, nbf);

    // 4) fused MFMA flash attention (builtin PV MFMA) -> abuf
    attn_mfma<<<448, 1024, 0, stream>>>(qbuf, kbuf, vbuf, mask, abuf);

    // 5) combine projection (MFMA, bias, bf16 out into mhbuf)
    mfma_gemm<true, true><<<400, 256, 0, stream>>>(abuf, WcombT, bcomb, mhbuf);

    // 6) fused pointer logits + softmax (bf16 nodes from nbf) -> out
    logits_softmax<<<448, 1024, 0, stream>>>(mhbuf, nbf, mask, out);
}

// Round 21
// 250.150 us; speedup vs baseline: 1.1542x; 1.1075x over previous
//
#include <hip/hip_runtime.h>
#include <hip/hip_bf16.h>
#include <math.h>

// Problem constants (from reference)
#define B_  64
#define P_  100
#define N_  1000
#define EMB_ 256
#define H_  16
#define D_  16
#define CTX_ 1024
#define L2E 1.44269504088896340736f
#define LROW 264   // LDS row stride (elems): 264*2B=528B, 132 dwords = 4 mod 32
                   // -> 16-lane b128 reads are 2-way bank-aliased (free, m136)

#if __has_builtin(__builtin_amdgcn_exp2f)
#define EXP2F(x) __builtin_amdgcn_exp2f(x)
#else
#define EXP2F(x) exp2f(x)
#endif

typedef __bf16 bf16_t;
typedef bf16_t bf16x8 __attribute__((ext_vector_type(8)));
typedef bf16_t bf16x4 __attribute__((ext_vector_type(4)));
typedef float  f32x4  __attribute__((ext_vector_type(4)));
typedef short  s16x4  __attribute__((ext_vector_type(4)));

// PV MFMA via builtin when available (R16-proven correct/neutral);
// asm fallback with manual hazard fences otherwise.
#if __has_builtin(__builtin_amdgcn_mfma_f32_16x16x16bf16_1k)
__device__ __forceinline__ void pv_mfma16(bf16x4 a, bf16x4 b, f32x4& c)
{
    s16x4 ai, bi;
    __builtin_memcpy(&ai, &a, 8);
    __builtin_memcpy(&bi, &b, 8);
    c = __builtin_amdgcn_mfma_f32_16x16x16bf16_1k(ai, bi, c, 0, 0, 0);
}
__device__ __forceinline__ void mfma_hazard_fence() {}
#else
__device__ __forceinline__ void pv_mfma16(bf16x4 a, bf16x4 b, f32x4& c)
{
    asm("s_nop 1\n\tv_mfma_f32_16x16x16_bf16 %0, %1, %2, %0"
        : "+v"(c) : "v"(a), "v"(b));
}
__device__ __forceinline__ void mfma_hazard_fence()
{
    __builtin_amdgcn_sched_barrier(0);
    asm volatile("s_nop 7\n\ts_nop 3");
}
#endif

// Load 8 consecutive f32 and convert to bf16x8 in-register.
__device__ __forceinline__ bf16x8 ldcvt8(const float* __restrict__ p)
{
    float4 u = *(const float4*)p;
    float4 v = *(const float4*)(p + 4);
    bf16x8 r;
    r[0] = (bf16_t)u.x; r[1] = (bf16_t)u.y; r[2] = (bf16_t)u.z; r[3] = (bf16_t)u.w;
    r[4] = (bf16_t)v.x; r[5] = (bf16_t)v.y; r[6] = (bf16_t)v.z; r[7] = (bf16_t)v.w;
    return r;
}

// ---------------------------------------------------------------------------
// Transpose four 256x256 f32 weights -> bf16 WT[n][k]
// ---------------------------------------------------------------------------
__global__ __launch_bounds__(256) void wtrans_kernel(
    const float* __restrict__ W0, const float* __restrict__ W1,
    const float* __restrict__ W2, const float* __restrict__ W3,
    bf16_t* __restrict__ T0, bf16_t* __restrict__ T1,
    bf16_t* __restrict__ T2, bf16_t* __restrict__ T3)
{
    __shared__ float t[32][33];
    const float* W = (blockIdx.z == 0) ? W0 : (blockIdx.z == 1) ? W1
                   : (blockIdx.z == 2) ? W2 : W3;
    bf16_t*      T = (blockIdx.z == 0) ? T0 : (blockIdx.z == 1) ? T1
                   : (blockIdx.z == 2) ? T2 : T3;
    const int n0 = blockIdx.x * 32, k0 = blockIdx.y * 32;
    const int tx = threadIdx.x & 31, ty = threadIdx.x >> 5;   // ty 0..7
#pragma unroll
    for (int i = 0; i < 4; ++i)
        t[ty + i * 8][tx] = W[(size_t)(k0 + ty + i * 8) * 256 + n0 + tx];
    __syncthreads();
#pragma unroll
    for (int i = 0; i < 4; ++i)
        T[(size_t)(n0 + ty + i * 8) * 256 + k0 + tx] = (bf16_t)t[tx][ty + i * 8];
}

// ---------------------------------------------------------------------------
// MFMA GEMM (bf16 A): C[M,256] = A[M,256] @ BT[256,256]^T.
// ---------------------------------------------------------------------------
template<bool BIAS, bool OUT_BF16>
__global__ __launch_bounds__(256) void mfma_gemm(
    const bf16_t* __restrict__ A, const bf16_t* __restrict__ BT,
    const float* __restrict__ bias, void* __restrict__ Cout)
{
    const int wave = threadIdx.x >> 6;
    const int lane = threadIdx.x & 63;
    const int m0 = blockIdx.x * 16;
    const int n0 = wave * 64;
    const int lr = lane & 15;
    const int lk = (lane >> 4) * 8;

    const bf16_t* ap = A  + (size_t)(m0 + lr) * 256 + lk;
    const bf16_t* bp = BT + (size_t)(n0 + lr) * 256 + lk;

    f32x4 acc[4];
#pragma unroll
    for (int j = 0; j < 4; ++j) acc[j] = (f32x4)0.f;

#pragma unroll 2
    for (int k0 = 0; k0 < 256; k0 += 32) {
        bf16x8 a = *(const bf16x8*)(ap + k0);
#pragma unroll
        for (int j = 0; j < 4; ++j) {
            bf16x8 b = *(const bf16x8*)(bp + (size_t)j * 16 * 256 + k0);
            acc[j] = __builtin_amdgcn_mfma_f32_16x16x32_bf16(a, b, acc[j], 0, 0, 0);
        }
    }

    const int crow = m0 + (lane >> 4) * 4;
#pragma unroll
    for (int j = 0; j < 4; ++j) {
        const int col = n0 + j * 16 + lr;
        const float bv = BIAS ? bias[col] : 0.f;
#pragma unroll
        for (int r = 0; r < 4; ++r) {
            float val = acc[j][r] + bv;
            if (OUT_BF16)
                ((bf16_t*)Cout)[(size_t)(crow + r) * 256 + col] = (bf16_t)val;
            else
                ((float*)Cout)[(size_t)(crow + r) * 256 + col] = val;
        }
    }
}

// ---------------------------------------------------------------------------
// q-path GEMM, f32 A with in-register cvt, fused fixup epilogue.
// ---------------------------------------------------------------------------
__global__ __launch_bounds__(256) void mfma_gemm_q(
    const float* __restrict__ A, const bf16_t* __restrict__ BT,
    const float* __restrict__ qcpart, const float* __restrict__ attr,
    const float* __restrict__ Wq, float* __restrict__ Cout)
{
    const int wave = threadIdx.x >> 6;
    const int lane = threadIdx.x & 63;
    const int m0 = blockIdx.x * 16;
    const int n0 = wave * 64;
    const int lr = lane & 15;
    const int lk = (lane >> 4) * 8;

    const float*  ap = A  + (size_t)(m0 + lr) * 256 + lk;
    const bf16_t* bp = BT + (size_t)(n0 + lr) * 256 + lk;

    f32x4 acc[4];
#pragma unroll
    for (int j = 0; j < 4; ++j) acc[j] = (f32x4)0.f;

#pragma unroll 2
    for (int k0 = 0; k0 < 256; k0 += 32) {
        bf16x8 a = ldcvt8(ap + k0);
#pragma unroll
        for (int j = 0; j < 4; ++j) {
            bf16x8 b = *(const bf16x8*)(bp + (size_t)j * 16 * 256 + k0);
            acc[j] = __builtin_amdgcn_mfma_f32_16x16x32_bf16(a, b, acc[j], 0, 0, 0);
        }
    }

    const int crow = m0 + (lane >> 4) * 4;
#pragma unroll
    for (int j = 0; j < 4; ++j) {
        const int col = n0 + j * 16 + lr;
#pragma unroll
        for (int r = 0; r < 4; ++r) {
            const int row = crow + r;         // < 6400
            const int b = row / P_;
            float add = 0.f;
#pragma unroll
            for (int kc = 0; kc < 4; ++kc)
                add += qcpart[((size_t)kc * 64 + b) * EMB_ + col];
            add = fmaf(attr[(size_t)row * 4 + 0], Wq[(size_t)256 * EMB_ + col], add);
            add = fmaf(attr[(size_t)row * 4 + 1], Wq[(size_t)257 * EMB_ + col], add);
            add = fmaf(attr[(size_t)row * 4 + 2], Wq[(size_t)258 * EMB_ + col], add);
            add = fmaf(attr[(size_t)row * 4 + 3], Wq[(size_t)259 * EMB_ + col], add);
            Cout[(size_t)row * 256 + col] = acc[j][r] + add;
        }
    }
}

// ---------------------------------------------------------------------------
// Fused K+V projection + nodes cvt (R17-proven): 4 m-tiles per wave, grid
// 1000; wave 0 stores nbf inside the k-loop. Swapped-operand MFMA ->
// coalesced bf16x4 stores.
// ---------------------------------------------------------------------------
__global__ __launch_bounds__(256) void mfma_gemm_kv(
    const float* __restrict__ A, const bf16_t* __restrict__ BTk,
    const bf16_t* __restrict__ BTv,
    bf16_t* __restrict__ Ck, bf16_t* __restrict__ Cv,
    bf16_t* __restrict__ nbf)
{
    const int wave = threadIdx.x >> 6;
    const int lane = threadIdx.x & 63;
    const int m0 = blockIdx.x * 64;          // grid 1000 (64000 rows)
    const int n0 = wave * 64;
    const int lr = lane & 15;
    const int lk = (lane >> 4) * 8;

    const float* ap[4];
    bf16_t* np[4];
#pragma unroll
    for (int m = 0; m < 4; ++m) {
        ap[m] = A   + (size_t)(m0 + m * 16 + lr) * 256 + lk;
        np[m] = nbf + (size_t)(m0 + m * 16 + lr) * 256 + lk;
    }
    const bf16_t* bpk = BTk + (size_t)(n0 + lr) * 256 + lk;
    const bf16_t* bpv = BTv + (size_t)(n0 + lr) * 256 + lk;

    f32x4 acck[4][4], accv[4][4];
#pragma unroll
    for (int m = 0; m < 4; ++m)
#pragma unroll
        for (int j = 0; j < 4; ++j) { acck[m][j] = (f32x4)0.f; accv[m][j] = (f32x4)0.f; }

    for (int k0 = 0; k0 < 256; k0 += 32) {
        bf16x8 a0 = ldcvt8(ap[0] + k0);
        bf16x8 a1 = ldcvt8(ap[1] + k0);
        bf16x8 a2 = ldcvt8(ap[2] + k0);
        bf16x8 a3 = ldcvt8(ap[3] + k0);
        if (wave == 0) {                      // fused nodes->bf16 store
            *(bf16x8*)(np[0] + k0) = a0;
            *(bf16x8*)(np[1] + k0) = a1;
            *(bf16x8*)(np[2] + k0) = a2;
            *(bf16x8*)(np[3] + k0) = a3;
        }
#pragma unroll
        for (int j = 0; j < 4; ++j) {
            bf16x8 bk = *(const bf16x8*)(bpk + (size_t)j * 16 * 256 + k0);
            bf16x8 bv = *(const bf16x8*)(bpv + (size_t)j * 16 * 256 + k0);
            acck[0][j] = __builtin_amdgcn_mfma_f32_16x16x32_bf16(bk, a0, acck[0][j], 0, 0, 0);
            acck[1][j] = __builtin_amdgcn_mfma_f32_16x16x32_bf16(bk, a1, acck[1][j], 0, 0, 0);
            acck[2][j] = __builtin_amdgcn_mfma_f32_16x16x32_bf16(bk, a2, acck[2][j], 0, 0, 0);
            acck[3][j] = __builtin_amdgcn_mfma_f32_16x16x32_bf16(bk, a3, acck[3][j], 0, 0, 0);
            accv[0][j] = __builtin_amdgcn_mfma_f32_16x16x32_bf16(bv, a0, accv[0][j], 0, 0, 0);
            accv[1][j] = __builtin_amdgcn_mfma_f32_16x16x32_bf16(bv, a1, accv[1][j], 0, 0, 0);
            accv[2][j] = __builtin_amdgcn_mfma_f32_16x16x32_bf16(bv, a2, accv[2][j], 0, 0, 0);
            accv[3][j] = __builtin_amdgcn_mfma_f32_16x16x32_bf16(bv, a3, accv[3][j], 0, 0, 0);
        }
    }

    const int lg4 = (lane >> 4) * 4;
#pragma unroll
    for (int m = 0; m < 4; ++m) {
        const size_t rowoff = (size_t)(m0 + m * 16 + lr) * 256;
#pragma unroll
        for (int j = 0; j < 4; ++j) {
            const int col = n0 + j * 16 + lg4;
            bf16x4 ok, ov;
#pragma unroll
            for (int r = 0; r < 4; ++r) {
                ok[r] = (bf16_t)acck[m][j][r];
                ov[r] = (bf16_t)accv[m][j][r];
            }
            *(bf16x4*)(Ck + rowoff + col) = ok;
            *(bf16x4*)(Cv + rowoff + col) = ov;
        }
    }
}

// ---------------------------------------------------------------------------
// qc partials: qcpart[kc][b][n] = sum_{k in chunk kc} ctx[b][k]*Wq[260+k][n]
// ---------------------------------------------------------------------------
__global__ __launch_bounds__(256) void qc_kernel(
    const float* __restrict__ ctx, const float* __restrict__ Wq,
    float* __restrict__ qcpart)
{
    const int b = blockIdx.x;
    const int kc = blockIdx.y;
    const int tid = threadIdx.x;
    const float* c = ctx + (size_t)b * CTX_ + kc * 256;
    const float* w = Wq + (size_t)(260 + kc * 256) * EMB_ + tid;
    float acc = 0.f;
#pragma unroll 8
    for (int kk = 0; kk < 256; ++kk)
        acc = fmaf(c[kk], w[(size_t)kk * EMB_], acc);
    qcpart[((size_t)kc * 64 + b) * EMB_ + tid] = acc;
}

// ---------------------------------------------------------------------------
// MFMA flash attention v20: cooperative LDS staging. Each 16-key chunk's
// K and V rows (16KB) are staged by ALL 1024 threads (one 16B load +
// ds_write each), double-buffered; waves then read fragments from LDS.
// Per-wave VMEM drops 6 -> 1 (mask) per chunk; K's 2x cross-wave read
// redundancy disappears. One barrier per chunk; stage(t+1) issues before
// compute(t), so HBM latency hides under compute at block scope.
// defer-max + dual state (chunk parity) retained. Grid 448 x 1024.
// ---------------------------------------------------------------------------
struct AttnState { float m, l; f32x4 acc; };

template<bool TAIL>
__device__ __forceinline__ void attn_chunk_lds(
    int n0, const bf16_t* __restrict__ skb, const bf16_t* __restrict__ svb,
    const float* __restrict__ maskrow, bf16x8 qfrag, int h, int lr, int lg,
    AttnState& st)
{
    // K A-frag from LDS: row lr, cols h*16 + (lg&1)*8 .. +8 ; zero for lg>=2
    bf16x8 ak = *(const bf16x8*)(skb + lr * LROW + h * 16 + (lg & 1) * 8);
    if (lg >= 2) ak = (bf16x8)(bf16_t)0.0f;

    f32x4 sc = __builtin_amdgcn_mfma_f32_16x16x32_bf16(ak, qfrag, (f32x4)0.f, 0, 0, 0);

    // scores + mask (lane's 4 keys n = n0+4*lg+r, query p = lr)
    int nm = n0 + 4 * lg;
    if (TAIL) nm = (nm < 996) ? nm : 996;
    float4 mk = *(const float4*)&maskrow[nm];
    float s0 = fmaf(sc[0], 0.25f, mk.x);
    float s1 = fmaf(sc[1], 0.25f, mk.y);
    float s2 = fmaf(sc[2], 0.25f, mk.z);
    float s3 = fmaf(sc[3], 0.25f, mk.w);
    if (TAIL) {
        if (n0 + 4 * lg + 0 >= N_) s0 = -3.0e38f;
        if (n0 + 4 * lg + 1 >= N_) s1 = -3.0e38f;
        if (n0 + 4 * lg + 2 >= N_) s2 = -3.0e38f;
        if (n0 + 4 * lg + 3 >= N_) s3 = -3.0e38f;
    }

    // defer-max: common path is per-lane only (no cross-lane ops)
    float tmax = fmaxf(fmaxf(s0, s1), fmaxf(s2, s3));
    if (__any(tmax > st.m + 8.0f)) {        // rare (~once per state)
        float rmax = fmaxf(tmax, __shfl_xor(tmax, 16));
        rmax = fmaxf(rmax, __shfl_xor(rmax, 32));
        float mn = fmaxf(st.m, rmax);
        mfma_hazard_fence();                // no-op on builtin path
        float f = EXP2F((st.m - mn) * L2E); // first time: exp2(-inf)=0
        st.l *= f;
        st.acc *= f;
        st.m = mn;
    }
    float w0 = EXP2F((s0 - st.m) * L2E);    // bounded by e^8
    float w1 = EXP2F((s1 - st.m) * L2E);
    float w2 = EXP2F((s2 - st.m) * L2E);
    float w3 = EXP2F((s3 - st.m) * L2E);
    st.l += (w0 + w1) + (w2 + w3);
    bf16x4 pb;
    pb[0] = (bf16_t)w0; pb[1] = (bf16_t)w1; pb[2] = (bf16_t)w2; pb[3] = (bf16_t)w3;

    // V^T A-frag from LDS: rows 4*lg..4*lg+3, col h*16+lr
    bf16x4 av;
#pragma unroll
    for (int i = 0; i < 4; ++i)
        av[i] = svb[(4 * lg + i) * LROW + h * 16 + lr];
    pv_mfma16(av, pb, st.acc);
}

__global__ __launch_bounds__(1024) void attn_mfma(
    const float* __restrict__ q, const bf16_t* __restrict__ k,
    const bf16_t* __restrict__ v, const float* __restrict__ mask,
    bf16_t* __restrict__ abuf)
{
    __shared__ bf16_t sk[2][16][LROW];   // 2 x 16 x 264 x 2B = 16,896 B
    __shared__ bf16_t sv[2][16][LROW];   // total 33,792 B

    // XCD-bijective block mapping: 448 = 8 xcd * 56 slots; 56 = 8 b-groups * 7
    const int x = blockIdx.x;
    const int xcd = x & 7;
    const int slot = x >> 3;                 // 0..55
    const int b = xcd + 8 * (slot / 7);
    const int mtile = slot % 7;
    const int h = threadIdx.x >> 6;          // wave = head
    const int lane = threadIdx.x & 63;
    const int p0 = mtile * 16;
    const int lr = lane & 15;
    const int lg = lane >> 4;

    // staging role (all 1024 threads): half 0 stages K, half 1 stages V
    const int tid = threadIdx.x;
    const int sh  = tid >> 9;                // 0 = K, 1 = V
    const int t2  = tid & 511;
    const int srow = t2 >> 5;                // 0..15
    const int scol = (t2 & 31) * 8;          // 0..248 (16B units)

    // Q B-frag (x32): col p = lr, k(d) = 8*lg+i ; zero for lg>=2
    const int pq = (p0 + lr < P_) ? (p0 + lr) : (P_ - 1);
    bf16x8 qfrag = (bf16x8)(bf16_t)0.0f;
    if (lg < 2) {
        const float* qp = q + ((size_t)b * P_ + pq) * 256 + h * 16 + lg * 8;
        float4 q0 = *(const float4*)qp;
        float4 q1 = *(const float4*)(qp + 4);
        qfrag[0] = (bf16_t)q0.x; qfrag[1] = (bf16_t)q0.y;
        qfrag[2] = (bf16_t)q0.z; qfrag[3] = (bf16_t)q0.w;
        qfrag[4] = (bf16_t)q1.x; qfrag[5] = (bf16_t)q1.y;
        qfrag[6] = (bf16_t)q1.z; qfrag[7] = (bf16_t)q1.w;
    }

    const bf16_t* kfull = k + (size_t)b * N_ * 256;
    const bf16_t* vfull = v + (size_t)b * N_ * 256;
    const bf16_t* sbase = sh ? vfull : kfull;
    const float* maskrow = mask + ((size_t)b * P_ + pq) * N_;

    AttnState stA, stB;
    stA.m = -INFINITY; stA.l = 0.f; stA.acc = (f32x4)0.f;
    stB.m = -INFINITY; stB.l = 0.f; stB.acc = (f32x4)0.f;

    // prologue: stage chunk 0 into buf 0
    {
        const bf16_t* src = sbase + (size_t)srow * 256 + scol;
        bf16_t* dst = sh ? &sv[0][srow][scol] : &sk[0][srow][scol];
        *(bf16x8*)dst = *(const bf16x8*)src;
    }
    __syncthreads();

    // 63 chunks total; chunks 0..61 in the loop, chunk 62 (tail) after.
    for (int it = 0; it < 62; ++it) {
        // stage chunk it+1 into the other buffer (rows clamped for tail)
        {
            const int rr = min((it + 1) * 16 + srow, N_ - 1);
            const bf16_t* src = sbase + (size_t)rr * 256 + scol;
            bf16_t* dst = sh ? &sv[(it + 1) & 1][srow][scol]
                             : &sk[(it + 1) & 1][srow][scol];
            *(bf16x8*)dst = *(const bf16x8*)src;
        }
        // compute chunk it from buf[it&1]; even chunks -> A, odd -> B
        if (it & 1)
            attn_chunk_lds<false>(it * 16, &sk[it & 1][0][0], &sv[it & 1][0][0],
                                  maskrow, qfrag, h, lr, lg, stB);
        else
            attn_chunk_lds<false>(it * 16, &sk[it & 1][0][0], &sv[it & 1][0][0],
                                  maskrow, qfrag, h, lr, lg, stA);
        __syncthreads();
    }
    // tail chunk 62 (n0=992) from buf 0 (staged at it=61; rows >=1000 are
    // clamped dup data, zeroed by the TAIL score masking)
    attn_chunk_lds<true>(992, &sk[0][0][0], &sv[0][0][0],
                         maskrow, qfrag, h, lr, lg, stA);

    // merge the two states (flash combine)
    mfma_hazard_fence();                      // no-op on builtin path
    float mn = fmaxf(stA.m, stB.m);
    float fA = EXP2F((stA.m - mn) * L2E);
    float fB = EXP2F((stB.m - mn) * L2E);
    float l = stA.l * fA + stB.l * fB;
    f32x4 acc = stA.acc * fA + stB.acc * fB;

    // row sum of l across the 4 lanes sharing lr
    float L = l + __shfl_xor(l, 16);
    L += __shfl_xor(L, 32);

    if (p0 + lr < P_) {
        float inv = 1.0f / L;
        bf16x4 o;
        o[0] = (bf16_t)(acc[0] * inv);
        o[1] = (bf16_t)(acc[1] * inv);
        o[2] = (bf16_t)(acc[2] * inv);
        o[3] = (bf16_t)(acc[3] * inv);
        // out^T: lane holds out[p=lr][d=4*lg+r]
        *(bf16x4*)(abuf + ((size_t)b * P_ + p0 + lr) * 256 + h * 16 + 4 * lg) = o;
    }
}

// ---------------------------------------------------------------------------
// Fused pointer logits + row softmax (bf16 nodes operand). Grid 448 x 1024.
// ---------------------------------------------------------------------------
__global__ __launch_bounds__(1024) void logits_softmax(
    const bf16_t* __restrict__ mh, const bf16_t* __restrict__ nodes,
    const float* __restrict__ mask, float* __restrict__ out)
{
    __shared__ float redm[16][16];
    __shared__ float reds[16][16];

    // XCD-bijective: 448 = 8 xcd * 56; 56 = 8 b-groups * 7 mtiles
    const int x = blockIdx.x;
    const int xcd = x & 7;
    const int slot = x >> 3;                 // 0..55
    const int b = xcd + 8 * (slot / 7);
    const int mt = slot % 7;
    const int wave = threadIdx.x >> 6;       // ngrp 0..15
    const int lane = threadIdx.x & 63;
    const int p0 = mt * 16;
    const int n0 = wave * 64;
    const int lr = lane & 15;
    const int lg = lane >> 4;
    const int lk = lg * 8;

    const bf16_t* bbase = nodes + (size_t)b * N_ * 256;
    int nrow[4];
#pragma unroll
    for (int j = 0; j < 4; ++j) {
        int n = n0 + j * 16 + lr;
        nrow[j] = (n < N_) ? n : (N_ - 1);
    }
    const bf16_t* ap = mh + ((size_t)(b * P_) + p0 + lr) * 256 + lk;

    f32x4 acc[4];
#pragma unroll
    for (int j = 0; j < 4; ++j) acc[j] = (f32x4)0.f;

#pragma unroll 2
    for (int k0 = 0; k0 < 256; k0 += 32) {
        bf16x8 a = *(const bf16x8*)(ap + k0);
#pragma unroll
        for (int j = 0; j < 4; ++j) {
            bf16x8 bfr = *(const bf16x8*)(bbase + (size_t)nrow[j] * 256 + lk + k0);
            acc[j] = __builtin_amdgcn_mfma_f32_16x16x32_bf16(a, bfr, acc[j], 0, 0, 0);
        }
    }

    // logits: 10*tanh(s/16) + mask; invalid n -> -3e38 (excluded from softmax)
    const int prowb = p0 + lg * 4;
    float lv[4][4];
#pragma unroll
    for (int j = 0; j < 4; ++j) {
        const int n = n0 + j * 16 + lr;
        const int nc = (n < N_) ? n : (N_ - 1);
#pragma unroll
        for (int r = 0; r < 4; ++r) {
            const int p = prowb + r;
            const int pc = (p < P_) ? p : (P_ - 1);
            float xv = acc[j][r] * (1.0f / 16.0f);
            float e = EXP2F(xv * (2.0f * L2E));
            float t = 1.0f - 2.0f / (e + 1.0f);
            float val = 10.0f * t + mask[((size_t)(b * P_ + pc)) * N_ + nc];
            lv[j][r] = (n < N_) ? val : -3.0e38f;
        }
    }

    // row max: over j (in-thread), lr (shfl within 16-lane group), waves (LDS)
    float pm[4];
#pragma unroll
    for (int r = 0; r < 4; ++r) {
        pm[r] = fmaxf(fmaxf(lv[0][r], lv[1][r]), fmaxf(lv[2][r], lv[3][r]));
        pm[r] = fmaxf(pm[r], __shfl_xor(pm[r], 1));
        pm[r] = fmaxf(pm[r], __shfl_xor(pm[r], 2));
        pm[r] = fmaxf(pm[r], __shfl_xor(pm[r], 4));
        pm[r] = fmaxf(pm[r], __shfl_xor(pm[r], 8));
    }
    if (lr == 0) {
#pragma unroll
        for (int r = 0; r < 4; ++r) redm[wave][lg * 4 + r] = pm[r];
    }
    __syncthreads();
    float gm[4];
#pragma unroll
    for (int r = 0; r < 4; ++r) {
        float m_ = redm[0][lg * 4 + r];
#pragma unroll
        for (int w = 1; w < 16; ++w) m_ = fmaxf(m_, redm[w][lg * 4 + r]);
        gm[r] = m_;
    }

    // exp + row sum (same reduction path)
    float ps[4];
#pragma unroll
    for (int r = 0; r < 4; ++r) ps[r] = 0.f;
#pragma unroll
    for (int j = 0; j < 4; ++j)
#pragma unroll
        for (int r = 0; r < 4; ++r) {
            float e = EXP2F((lv[j][r] - gm[r]) * L2E);   // -3e38 -> 0
            lv[j][r] = e;
            ps[r] += e;
        }
#pragma unroll
    for (int r = 0; r < 4; ++r) {
        ps[r] += __shfl_xor(ps[r], 1);
        ps[r] += __shfl_xor(ps[r], 2);
        ps[r] += __shfl_xor(ps[r], 4);
        ps[r] += __shfl_xor(ps[r], 8);
    }
    if (lr == 0) {
#pragma unroll
        for (int r = 0; r < 4; ++r) reds[wave][lg * 4 + r] = ps[r];
    }
    __syncthreads();
    float inv[4];
#pragma unroll
    for (int r = 0; r < 4; ++r) {
        float s = 0.f;
#pragma unroll
        for (int w = 0; w < 16; ++w) s += reds[w][lg * 4 + r];
        inv[r] = 1.0f / s;
    }

    // normalized writes (each (b,p,n) exactly once)
#pragma unroll
    for (int j = 0; j < 4; ++j) {
        const int n = n0 + j * 16 + lr;
        if (n >= N_) continue;
#pragma unroll
        for (int r = 0; r < 4; ++r) {
            const int p = prowb + r;
            if (p >= P_) continue;
            out[((size_t)(b * P_ + p)) * N_ + n] = lv[j][r] * inv[r];
        }
    }
}

// ---------------------------------------------------------------------------
extern "C" void kernel_launch(void* const* d_in, const int* in_sizes, int n_in,
                              void* d_out, int out_size, void* d_ws, size_t ws_size,
                              hipStream_t stream)
{
    const float* lastnode = (const float*)d_in[0];   // [B,P,256]
    const float* attr     = (const float*)d_in[1];   // [B,P,4]
    const float* ctx      = (const float*)d_in[2];   // [B,1024]
    const float* mask     = (const float*)d_in[3];   // [B,P,N]
    const float* nodes    = (const float*)d_in[4];   // [B,N,256]
    const float* Wq       = (const float*)d_in[5];   // [1284,256]
    const float* Wk       = (const float*)d_in[6];   // [256,256]
    const float* Wv       = (const float*)d_in[7];   // [256,256]
    const float* Wcomb    = (const float*)d_in[8];   // [256,256]
    const float* bcomb    = (const float*)d_in[9];   // [256]
    float* out = (float*)d_out;

    // Workspace layout (offsets in floats). Total 27,230,208 f = 108.9 MB.
    float* ws = (float*)d_ws;
    bf16_t* kbuf   = (bf16_t*)(ws);                   // 16,384,000 bf16
    bf16_t* vbuf   = (bf16_t*)(ws + 8192000);         // 16,384,000 bf16
    float*  qbuf   = ws + 16384000;                   // 1,638,400 f
    bf16_t* nbf    = (bf16_t*)(ws + 18022400);        // 16,384,000 bf16
    bf16_t* WkT    = (bf16_t*)(ws + 26214400);        // 65,536 bf16
    bf16_t* WvT    = (bf16_t*)(ws + 26247168);        // 65,536 bf16
    bf16_t* WcombT = (bf16_t*)(ws + 26279936);        // 65,536 bf16
    bf16_t* WqmT   = (bf16_t*)(ws + 26312704);        // 65,536 bf16
    float*  qcpart = ws + 26345472;                   // 65,536 f (4x64x256)
    bf16_t* abuf   = (bf16_t*)(ws + 26411008);        // 1,638,400 bf16
    // Overlay: mhbuf reuses kbuf (K dead after attn_mfma); logits reads rows
    // up to b*100+111 -> slack is inside kbuf's 64000 rows.
    bf16_t* mhbuf = kbuf;

    // 1) weight transposes -> bf16 (Wk, Wv, Wcomb, Wq[0:256))
    wtrans_kernel<<<dim3(8, 8, 4), 256, 0, stream>>>(
        Wk, Wv, Wcomb, Wq, WkT, WvT, WcombT, WqmT);

    // 2) q pipeline: ctx partials + fused GEMM/fixup (f32 A, in-register cvt)
    qc_kernel<<<dim3(64, 4), 256, 0, stream>>>(ctx, Wq, qcpart);
    mfma_gemm_q<<<400, 256, 0, stream>>>(lastnode, WqmT, qcpart, attr, Wq, qbuf);

    // 3) fused k+v projection + nodes cvt, 4 m-tiles/wave (grid 1000)
    mfma_gemm_kv<<<1000, 256, 0, stream>>>(nodes, WkT, WvT, kbuf, vbuf, nbf);

    // 4) fused MFMA flash attention (cooperative LDS staging) -> abuf
    attn_mfma<<<448, 1024, 0, stream>>>(qbuf, kbuf, vbuf, mask, abuf);

    // 5) combine projection (MFMA, bias, bf16 out into mhbuf)
    mfma_gemm<true, true><<<400, 256, 0, stream>>>(abuf, WcombT, bcomb, mhbuf);

    // 6) fused pointer logits + softmax (bf16 nodes from nbf) -> out
    logits_softmax<<<448, 1024, 0, stream>>>(mhbuf, nbf, mask, out);
}

// Round 22
// 227.456 us; speedup vs baseline: 1.2693x; 1.0998x over previous
//
#include <hip/hip_runtime.h>
#include <hip/hip_bf16.h>
#include <math.h>

// Problem constants (from reference)
#define B_  64
#define P_  100
#define N_  1000
#define EMB_ 256
#define H_  16
#define D_  16
#define CTX_ 1024
#define L2E 1.44269504088896340736f
#define LROW 264   // LDS row stride (elems): 264*2B=528B, 132 dwords = 4 mod 32
                   // -> 16-lane b128 reads are 2-way bank-aliased (free, m136)

#if __has_builtin(__builtin_amdgcn_exp2f)
#define EXP2F(x) __builtin_amdgcn_exp2f(x)
#else
#define EXP2F(x) exp2f(x)
#endif

typedef __bf16 bf16_t;
typedef bf16_t bf16x8 __attribute__((ext_vector_type(8)));
typedef bf16_t bf16x4 __attribute__((ext_vector_type(4)));
typedef float  f32x4  __attribute__((ext_vector_type(4)));
typedef short  s16x4  __attribute__((ext_vector_type(4)));

// PV MFMA via builtin when available (R16-proven correct/neutral);
// asm fallback with manual hazard fences otherwise.
#if __has_builtin(__builtin_amdgcn_mfma_f32_16x16x16bf16_1k)
__device__ __forceinline__ void pv_mfma16(bf16x4 a, bf16x4 b, f32x4& c)
{
    s16x4 ai, bi;
    __builtin_memcpy(&ai, &a, 8);
    __builtin_memcpy(&bi, &b, 8);
    c = __builtin_amdgcn_mfma_f32_16x16x16bf16_1k(ai, bi, c, 0, 0, 0);
}
__device__ __forceinline__ void mfma_hazard_fence() {}
#else
__device__ __forceinline__ void pv_mfma16(bf16x4 a, bf16x4 b, f32x4& c)
{
    asm("s_nop 1\n\tv_mfma_f32_16x16x16_bf16 %0, %1, %2, %0"
        : "+v"(c) : "v"(a), "v"(b));
}
__device__ __forceinline__ void mfma_hazard_fence()
{
    __builtin_amdgcn_sched_barrier(0);
    asm volatile("s_nop 7\n\ts_nop 3");
}
#endif

// Load 8 consecutive f32 and convert to bf16x8 in-register.
__device__ __forceinline__ bf16x8 ldcvt8(const float* __restrict__ p)
{
    float4 u = *(const float4*)p;
    float4 v = *(const float4*)(p + 4);
    bf16x8 r;
    r[0] = (bf16_t)u.x; r[1] = (bf16_t)u.y; r[2] = (bf16_t)u.z; r[3] = (bf16_t)u.w;
    r[4] = (bf16_t)v.x; r[5] = (bf16_t)v.y; r[6] = (bf16_t)v.z; r[7] = (bf16_t)v.w;
    return r;
}

// ---------------------------------------------------------------------------
// Transpose four 256x256 f32 weights -> bf16 WT[n][k]
// ---------------------------------------------------------------------------
__global__ __launch_bounds__(256) void wtrans_kernel(
    const float* __restrict__ W0, const float* __restrict__ W1,
    const float* __restrict__ W2, const float* __restrict__ W3,
    bf16_t* __restrict__ T0, bf16_t* __restrict__ T1,
    bf16_t* __restrict__ T2, bf16_t* __restrict__ T3)
{
    __shared__ float t[32][33];
    const float* W = (blockIdx.z == 0) ? W0 : (blockIdx.z == 1) ? W1
                   : (blockIdx.z == 2) ? W2 : W3;
    bf16_t*      T = (blockIdx.z == 0) ? T0 : (blockIdx.z == 1) ? T1
                   : (blockIdx.z == 2) ? T2 : T3;
    const int n0 = blockIdx.x * 32, k0 = blockIdx.y * 32;
    const int tx = threadIdx.x & 31, ty = threadIdx.x >> 5;   // ty 0..7
#pragma unroll
    for (int i = 0; i < 4; ++i)
        t[ty + i * 8][tx] = W[(size_t)(k0 + ty + i * 8) * 256 + n0 + tx];
    __syncthreads();
#pragma unroll
    for (int i = 0; i < 4; ++i)
        T[(size_t)(n0 + ty + i * 8) * 256 + k0 + tx] = (bf16_t)t[tx][ty + i * 8];
}

// ---------------------------------------------------------------------------
// MFMA GEMM (bf16 A): C[M,256] = A[M,256] @ BT[256,256]^T.
// ---------------------------------------------------------------------------
template<bool BIAS, bool OUT_BF16>
__global__ __launch_bounds__(256) void mfma_gemm(
    const bf16_t* __restrict__ A, const bf16_t* __restrict__ BT,
    const float* __restrict__ bias, void* __restrict__ Cout)
{
    const int wave = threadIdx.x >> 6;
    const int lane = threadIdx.x & 63;
    const int m0 = blockIdx.x * 16;
    const int n0 = wave * 64;
    const int lr = lane & 15;
    const int lk = (lane >> 4) * 8;

    const bf16_t* ap = A  + (size_t)(m0 + lr) * 256 + lk;
    const bf16_t* bp = BT + (size_t)(n0 + lr) * 256 + lk;

    f32x4 acc[4];
#pragma unroll
    for (int j = 0; j < 4; ++j) acc[j] = (f32x4)0.f;

#pragma unroll 2
    for (int k0 = 0; k0 < 256; k0 += 32) {
        bf16x8 a = *(const bf16x8*)(ap + k0);
#pragma unroll
        for (int j = 0; j < 4; ++j) {
            bf16x8 b = *(const bf16x8*)(bp + (size_t)j * 16 * 256 + k0);
            acc[j] = __builtin_amdgcn_mfma_f32_16x16x32_bf16(a, b, acc[j], 0, 0, 0);
        }
    }

    const int crow = m0 + (lane >> 4) * 4;
#pragma unroll
    for (int j = 0; j < 4; ++j) {
        const int col = n0 + j * 16 + lr;
        const float bv = BIAS ? bias[col] : 0.f;
#pragma unroll
        for (int r = 0; r < 4; ++r) {
            float val = acc[j][r] + bv;
            if (OUT_BF16)
                ((bf16_t*)Cout)[(size_t)(crow + r) * 256 + col] = (bf16_t)val;
            else
                ((float*)Cout)[(size_t)(crow + r) * 256 + col] = val;
        }
    }
}

// ---------------------------------------------------------------------------
// q-path GEMM, f32 A with in-register cvt, fused fixup epilogue.
// ---------------------------------------------------------------------------
__global__ __launch_bounds__(256) void mfma_gemm_q(
    const float* __restrict__ A, const bf16_t* __restrict__ BT,
    const float* __restrict__ qcpart, const float* __restrict__ attr,
    const float* __restrict__ Wq, float* __restrict__ Cout)
{
    const int wave = threadIdx.x >> 6;
    const int lane = threadIdx.x & 63;
    const int m0 = blockIdx.x * 16;
    const int n0 = wave * 64;
    const int lr = lane & 15;
    const int lk = (lane >> 4) * 8;

    const float*  ap = A  + (size_t)(m0 + lr) * 256 + lk;
    const bf16_t* bp = BT + (size_t)(n0 + lr) * 256 + lk;

    f32x4 acc[4];
#pragma unroll
    for (int j = 0; j < 4; ++j) acc[j] = (f32x4)0.f;

#pragma unroll 2
    for (int k0 = 0; k0 < 256; k0 += 32) {
        bf16x8 a = ldcvt8(ap + k0);
#pragma unroll
        for (int j = 0; j < 4; ++j) {
            bf16x8 b = *(const bf16x8*)(bp + (size_t)j * 16 * 256 + k0);
            acc[j] = __builtin_amdgcn_mfma_f32_16x16x32_bf16(a, b, acc[j], 0, 0, 0);
        }
    }

    const int crow = m0 + (lane >> 4) * 4;
#pragma unroll
    for (int j = 0; j < 4; ++j) {
        const int col = n0 + j * 16 + lr;
#pragma unroll
        for (int r = 0; r < 4; ++r) {
            const int row = crow + r;         // < 6400
            const int b = row / P_;
            float add = 0.f;
#pragma unroll
            for (int kc = 0; kc < 4; ++kc)
                add += qcpart[((size_t)kc * 64 + b) * EMB_ + col];
            add = fmaf(attr[(size_t)row * 4 + 0], Wq[(size_t)256 * EMB_ + col], add);
            add = fmaf(attr[(size_t)row * 4 + 1], Wq[(size_t)257 * EMB_ + col], add);
            add = fmaf(attr[(size_t)row * 4 + 2], Wq[(size_t)258 * EMB_ + col], add);
            add = fmaf(attr[(size_t)row * 4 + 3], Wq[(size_t)259 * EMB_ + col], add);
            Cout[(size_t)row * 256 + col] = acc[j][r] + add;
        }
    }
}

// ---------------------------------------------------------------------------
// Fused K+V projection + nodes cvt, v7 (R21): cooperative LDS-staged A.
// All 4 waves previously loaded IDENTICAL A rows from HBM (4x redundant
// VMEM, 8 serialized dependent iters -> latency wall, R20's kv at 100 us).
// Now: prologue stages the 64x256 A tile once (256 thr x 8 independent
// ldcvt8 -> bf16 LDS + nbf write-through), one barrier, then the k-loop
// reads A via ds_read_b128 (stride 264 elems -> 2-way alias, free) and
// B from L1/L2. Zero HBM loads inside the loop.
// ---------------------------------------------------------------------------
__global__ __launch_bounds__(256) void mfma_gemm_kv(
    const float* __restrict__ A, const bf16_t* __restrict__ BTk,
    const bf16_t* __restrict__ BTv,
    bf16_t* __restrict__ Ck, bf16_t* __restrict__ Cv,
    bf16_t* __restrict__ nbf)
{
    __shared__ bf16_t sA[64][LROW];          // 64 x 264 x 2B = 33,792 B

    const int tid  = threadIdx.x;
    const int wave = tid >> 6;
    const int lane = tid & 63;
    const int m0 = blockIdx.x * 64;          // grid 1000 (64000 rows)
    const int n0 = wave * 64;
    const int lr = lane & 15;
    const int lk = (lane >> 4) * 8;

    // cooperative A stage: 2048 chunks of 8 elems; 8 per thread, coalesced.
#pragma unroll
    for (int c = 0; c < 8; ++c) {
        const int chunk = tid + c * 256;     // 0..2047
        const int row = chunk >> 5;          // 0..63
        const int col = (chunk & 31) * 8;    // 0..248
        bf16x8 vv = ldcvt8(A + (size_t)(m0 + row) * 256 + col);
        *(bf16x8*)(&sA[row][col]) = vv;
        *(bf16x8*)(nbf + (size_t)(m0 + row) * 256 + col) = vv;   // fused cvt out
    }
    __syncthreads();

    const bf16_t* bpk = BTk + (size_t)(n0 + lr) * 256 + lk;
    const bf16_t* bpv = BTv + (size_t)(n0 + lr) * 256 + lk;

    f32x4 acck[4][4], accv[4][4];
#pragma unroll
    for (int m = 0; m < 4; ++m)
#pragma unroll
        for (int j = 0; j < 4; ++j) { acck[m][j] = (f32x4)0.f; accv[m][j] = (f32x4)0.f; }

    for (int k0 = 0; k0 < 256; k0 += 32) {
        bf16x8 a0 = *(const bf16x8*)(&sA[0 * 16 + lr][lk + k0]);
        bf16x8 a1 = *(const bf16x8*)(&sA[1 * 16 + lr][lk + k0]);
        bf16x8 a2 = *(const bf16x8*)(&sA[2 * 16 + lr][lk + k0]);
        bf16x8 a3 = *(const bf16x8*)(&sA[3 * 16 + lr][lk + k0]);
#pragma unroll
        for (int j = 0; j < 4; ++j) {
            bf16x8 bk = *(const bf16x8*)(bpk + (size_t)j * 16 * 256 + k0);
            bf16x8 bv = *(const bf16x8*)(bpv + (size_t)j * 16 * 256 + k0);
            // swapped: lane holds C[m0+m*16+lr][n0+j*16+4*lg .. +3]
            acck[0][j] = __builtin_amdgcn_mfma_f32_16x16x32_bf16(bk, a0, acck[0][j], 0, 0, 0);
            acck[1][j] = __builtin_amdgcn_mfma_f32_16x16x32_bf16(bk, a1, acck[1][j], 0, 0, 0);
            acck[2][j] = __builtin_amdgcn_mfma_f32_16x16x32_bf16(bk, a2, acck[2][j], 0, 0, 0);
            acck[3][j] = __builtin_amdgcn_mfma_f32_16x16x32_bf16(bk, a3, acck[3][j], 0, 0, 0);
            accv[0][j] = __builtin_amdgcn_mfma_f32_16x16x32_bf16(bv, a0, accv[0][j], 0, 0, 0);
            accv[1][j] = __builtin_amdgcn_mfma_f32_16x16x32_bf16(bv, a1, accv[1][j], 0, 0, 0);
            accv[2][j] = __builtin_amdgcn_mfma_f32_16x16x32_bf16(bv, a2, accv[2][j], 0, 0, 0);
            accv[3][j] = __builtin_amdgcn_mfma_f32_16x16x32_bf16(bv, a3, accv[3][j], 0, 0, 0);
        }
    }

    const int lg4 = (lane >> 4) * 4;
#pragma unroll
    for (int m = 0; m < 4; ++m) {
        const size_t rowoff = (size_t)(m0 + m * 16 + lr) * 256;
#pragma unroll
        for (int j = 0; j < 4; ++j) {
            const int col = n0 + j * 16 + lg4;
            bf16x4 ok, ov;
#pragma unroll
            for (int r = 0; r < 4; ++r) {
                ok[r] = (bf16_t)acck[m][j][r];
                ov[r] = (bf16_t)accv[m][j][r];
            }
            *(bf16x4*)(Ck + rowoff + col) = ok;
            *(bf16x4*)(Cv + rowoff + col) = ov;
        }
    }
}

// ---------------------------------------------------------------------------
// qc partials: qcpart[kc][b][n] = sum_{k in chunk kc} ctx[b][k]*Wq[260+k][n]
// ---------------------------------------------------------------------------
__global__ __launch_bounds__(256) void qc_kernel(
    const float* __restrict__ ctx, const float* __restrict__ Wq,
    float* __restrict__ qcpart)
{
    const int b = blockIdx.x;
    const int kc = blockIdx.y;
    const int tid = threadIdx.x;
    const float* c = ctx + (size_t)b * CTX_ + kc * 256;
    const float* w = Wq + (size_t)(260 + kc * 256) * EMB_ + tid;
    float acc = 0.f;
#pragma unroll 8
    for (int kk = 0; kk < 256; ++kk)
        acc = fmaf(c[kk], w[(size_t)kk * EMB_], acc);
    qcpart[((size_t)kc * 64 + b) * EMB_ + tid] = acc;
}

// ---------------------------------------------------------------------------
// MFMA flash attention v20 (R20-proven WIN): cooperative LDS staging,
// double-buffered; per-wave VMEM 6 -> 1 per chunk. Grid 448 x 1024.
// ---------------------------------------------------------------------------
struct AttnState { float m, l; f32x4 acc; };

template<bool TAIL>
__device__ __forceinline__ void attn_chunk_lds(
    int n0, const bf16_t* __restrict__ skb, const bf16_t* __restrict__ svb,
    const float* __restrict__ maskrow, bf16x8 qfrag, int h, int lr, int lg,
    AttnState& st)
{
    // K A-frag from LDS: row lr, cols h*16 + (lg&1)*8 .. +8 ; zero for lg>=2
    bf16x8 ak = *(const bf16x8*)(skb + lr * LROW + h * 16 + (lg & 1) * 8);
    if (lg >= 2) ak = (bf16x8)(bf16_t)0.0f;

    f32x4 sc = __builtin_amdgcn_mfma_f32_16x16x32_bf16(ak, qfrag, (f32x4)0.f, 0, 0, 0);

    // scores + mask (lane's 4 keys n = n0+4*lg+r, query p = lr)
    int nm = n0 + 4 * lg;
    if (TAIL) nm = (nm < 996) ? nm : 996;
    float4 mk = *(const float4*)&maskrow[nm];
    float s0 = fmaf(sc[0], 0.25f, mk.x);
    float s1 = fmaf(sc[1], 0.25f, mk.y);
    float s2 = fmaf(sc[2], 0.25f, mk.z);
    float s3 = fmaf(sc[3], 0.25f, mk.w);
    if (TAIL) {
        if (n0 + 4 * lg + 0 >= N_) s0 = -3.0e38f;
        if (n0 + 4 * lg + 1 >= N_) s1 = -3.0e38f;
        if (n0 + 4 * lg + 2 >= N_) s2 = -3.0e38f;
        if (n0 + 4 * lg + 3 >= N_) s3 = -3.0e38f;
    }

    // defer-max: common path is per-lane only (no cross-lane ops)
    float tmax = fmaxf(fmaxf(s0, s1), fmaxf(s2, s3));
    if (__any(tmax > st.m + 8.0f)) {        // rare (~once per state)
        float rmax = fmaxf(tmax, __shfl_xor(tmax, 16));
        rmax = fmaxf(rmax, __shfl_xor(rmax, 32));
        float mn = fmaxf(st.m, rmax);
        mfma_hazard_fence();                // no-op on builtin path
        float f = EXP2F((st.m - mn) * L2E); // first time: exp2(-inf)=0
        st.l *= f;
        st.acc *= f;
        st.m = mn;
    }
    float w0 = EXP2F((s0 - st.m) * L2E);    // bounded by e^8
    float w1 = EXP2F((s1 - st.m) * L2E);
    float w2 = EXP2F((s2 - st.m) * L2E);
    float w3 = EXP2F((s3 - st.m) * L2E);
    st.l += (w0 + w1) + (w2 + w3);
    bf16x4 pb;
    pb[0] = (bf16_t)w0; pb[1] = (bf16_t)w1; pb[2] = (bf16_t)w2; pb[3] = (bf16_t)w3;

    // V^T A-frag from LDS: rows 4*lg..4*lg+3, col h*16+lr
    bf16x4 av;
#pragma unroll
    for (int i = 0; i < 4; ++i)
        av[i] = svb[(4 * lg + i) * LROW + h * 16 + lr];
    pv_mfma16(av, pb, st.acc);
}

__global__ __launch_bounds__(1024) void attn_mfma(
    const float* __restrict__ q, const bf16_t* __restrict__ k,
    const bf16_t* __restrict__ v, const float* __restrict__ mask,
    bf16_t* __restrict__ abuf)
{
    __shared__ bf16_t sk[2][16][LROW];   // 2 x 16 x 264 x 2B = 16,896 B
    __shared__ bf16_t sv[2][16][LROW];   // total 33,792 B

    // XCD-bijective block mapping: 448 = 8 xcd * 56 slots; 56 = 8 b-groups * 7
    const int x = blockIdx.x;
    const int xcd = x & 7;
    const int slot = x >> 3;                 // 0..55
    const int b = xcd + 8 * (slot / 7);
    const int mtile = slot % 7;
    const int h = threadIdx.x >> 6;          // wave = head
    const int lane = threadIdx.x & 63;
    const int p0 = mtile * 16;
    const int lr = lane & 15;
    const int lg = lane >> 4;

    // staging role (all 1024 threads): half 0 stages K, half 1 stages V
    const int tid = threadIdx.x;
    const int sh  = tid >> 9;                // 0 = K, 1 = V
    const int t2  = tid & 511;
    const int srow = t2 >> 5;                // 0..15
    const int scol = (t2 & 31) * 8;          // 0..248 (16B units)

    // Q B-frag (x32): col p = lr, k(d) = 8*lg+i ; zero for lg>=2
    const int pq = (p0 + lr < P_) ? (p0 + lr) : (P_ - 1);
    bf16x8 qfrag = (bf16x8)(bf16_t)0.0f;
    if (lg < 2) {
        const float* qp = q + ((size_t)b * P_ + pq) * 256 + h * 16 + lg * 8;
        float4 q0 = *(const float4*)qp;
        float4 q1 = *(const float4*)(qp + 4);
        qfrag[0] = (bf16_t)q0.x; qfrag[1] = (bf16_t)q0.y;
        qfrag[2] = (bf16_t)q0.z; qfrag[3] = (bf16_t)q0.w;
        qfrag[4] = (bf16_t)q1.x; qfrag[5] = (bf16_t)q1.y;
        qfrag[6] = (bf16_t)q1.z; qfrag[7] = (bf16_t)q1.w;
    }

    const bf16_t* kfull = k + (size_t)b * N_ * 256;
    const bf16_t* vfull = v + (size_t)b * N_ * 256;
    const bf16_t* sbase = sh ? vfull : kfull;
    const float* maskrow = mask + ((size_t)b * P_ + pq) * N_;

    AttnState stA, stB;
    stA.m = -INFINITY; stA.l = 0.f; stA.acc = (f32x4)0.f;
    stB.m = -INFINITY; stB.l = 0.f; stB.acc = (f32x4)0.f;

    // prologue: stage chunk 0 into buf 0
    {
        const bf16_t* src = sbase + (size_t)srow * 256 + scol;
        bf16_t* dst = sh ? &sv[0][srow][scol] : &sk[0][srow][scol];
        *(bf16x8*)dst = *(const bf16x8*)src;
    }
    __syncthreads();

    // 63 chunks total; chunks 0..61 in the loop, chunk 62 (tail) after.
    for (int it = 0; it < 62; ++it) {
        // stage chunk it+1 into the other buffer (rows clamped for tail)
        {
            const int rr = min((it + 1) * 16 + srow, N_ - 1);
            const bf16_t* src = sbase + (size_t)rr * 256 + scol;
            bf16_t* dst = sh ? &sv[(it + 1) & 1][srow][scol]
                             : &sk[(it + 1) & 1][srow][scol];
            *(bf16x8*)dst = *(const bf16x8*)src;
        }
        // compute chunk it from buf[it&1]; even chunks -> A, odd -> B
        if (it & 1)
            attn_chunk_lds<false>(it * 16, &sk[it & 1][0][0], &sv[it & 1][0][0],
                                  maskrow, qfrag, h, lr, lg, stB);
        else
            attn_chunk_lds<false>(it * 16, &sk[it & 1][0][0], &sv[it & 1][0][0],
                                  maskrow, qfrag, h, lr, lg, stA);
        __syncthreads();
    }
    // tail chunk 62 (n0=992) from buf 0 (staged at it=61; rows >=1000 are
    // clamped dup data, zeroed by the TAIL score masking)
    attn_chunk_lds<true>(992, &sk[0][0][0], &sv[0][0][0],
                         maskrow, qfrag, h, lr, lg, stA);

    // merge the two states (flash combine)
    mfma_hazard_fence();                      // no-op on builtin path
    float mn = fmaxf(stA.m, stB.m);
    float fA = EXP2F((stA.m - mn) * L2E);
    float fB = EXP2F((stB.m - mn) * L2E);
    float l = stA.l * fA + stB.l * fB;
    f32x4 acc = stA.acc * fA + stB.acc * fB;

    // row sum of l across the 4 lanes sharing lr
    float L = l + __shfl_xor(l, 16);
    L += __shfl_xor(L, 32);

    if (p0 + lr < P_) {
        float inv = 1.0f / L;
        bf16x4 o;
        o[0] = (bf16_t)(acc[0] * inv);
        o[1] = (bf16_t)(acc[1] * inv);
        o[2] = (bf16_t)(acc[2] * inv);
        o[3] = (bf16_t)(acc[3] * inv);
        // out^T: lane holds out[p=lr][d=4*lg+r]
        *(bf16x4*)(abuf + ((size_t)b * P_ + p0 + lr) * 256 + h * 16 + 4 * lg) = o;
    }
}

// ---------------------------------------------------------------------------
// Fused pointer logits + row softmax (bf16 nodes operand). Grid 448 x 1024.
// ---------------------------------------------------------------------------
__global__ __launch_bounds__(1024) void logits_softmax(
    const bf16_t* __restrict__ mh, const bf16_t* __restrict__ nodes,
    const float* __restrict__ mask, float* __restrict__ out)
{
    __shared__ float redm[16][16];
    __shared__ float reds[16][16];

    // XCD-bijective: 448 = 8 xcd * 56; 56 = 8 b-groups * 7 mtiles
    const int x = blockIdx.x;
    const int xcd = x & 7;
    const int slot = x >> 3;                 // 0..55
    const int b = xcd + 8 * (slot / 7);
    const int mt = slot % 7;
    const int wave = threadIdx.x >> 6;       // ngrp 0..15
    const int lane = threadIdx.x & 63;
    const int p0 = mt * 16;
    const int n0 = wave * 64;
    const int lr = lane & 15;
    const int lg = lane >> 4;
    const int lk = lg * 8;

    const bf16_t* bbase = nodes + (size_t)b * N_ * 256;
    int nrow[4];
#pragma unroll
    for (int j = 0; j < 4; ++j) {
        int n = n0 + j * 16 + lr;
        nrow[j] = (n < N_) ? n : (N_ - 1);
    }
    const bf16_t* ap = mh + ((size_t)(b * P_) + p0 + lr) * 256 + lk;

    f32x4 acc[4];
#pragma unroll
    for (int j = 0; j < 4; ++j) acc[j] = (f32x4)0.f;

#pragma unroll 2
    for (int k0 = 0; k0 < 256; k0 += 32) {
        bf16x8 a = *(const bf16x8*)(ap + k0);
#pragma unroll
        for (int j = 0; j < 4; ++j) {
            bf16x8 bfr = *(const bf16x8*)(bbase + (size_t)nrow[j] * 256 + lk + k0);
            acc[j] = __builtin_amdgcn_mfma_f32_16x16x32_bf16(a, bfr, acc[j], 0, 0, 0);
        }
    }

    // logits: 10*tanh(s/16) + mask; invalid n -> -3e38 (excluded from softmax)
    const int prowb = p0 + lg * 4;
    float lv[4][4];
#pragma unroll
    for (int j = 0; j < 4; ++j) {
        const int n = n0 + j * 16 + lr;
        const int nc = (n < N_) ? n : (N_ - 1);
#pragma unroll
        for (int r = 0; r < 4; ++r) {
            const int p = prowb + r;
            const int pc = (p < P_) ? p : (P_ - 1);
            float xv = acc[j][r] * (1.0f / 16.0f);
            float e = EXP2F(xv * (2.0f * L2E));
            float t = 1.0f - 2.0f / (e + 1.0f);
            float val = 10.0f * t + mask[((size_t)(b * P_ + pc)) * N_ + nc];
            lv[j][r] = (n < N_) ? val : -3.0e38f;
        }
    }

    // row max: over j (in-thread), lr (shfl within 16-lane group), waves (LDS)
    float pm[4];
#pragma unroll
    for (int r = 0; r < 4; ++r) {
        pm[r] = fmaxf(fmaxf(lv[0][r], lv[1][r]), fmaxf(lv[2][r], lv[3][r]));
        pm[r] = fmaxf(pm[r], __shfl_xor(pm[r], 1));
        pm[r] = fmaxf(pm[r], __shfl_xor(pm[r], 2));
        pm[r] = fmaxf(pm[r], __shfl_xor(pm[r], 4));
        pm[r] = fmaxf(pm[r], __shfl_xor(pm[r], 8));
    }
    if (lr == 0) {
#pragma unroll
        for (int r = 0; r < 4; ++r) redm[wave][lg * 4 + r] = pm[r];
    }
    __syncthreads();
    float gm[4];
#pragma unroll
    for (int r = 0; r < 4; ++r) {
        float m_ = redm[0][lg * 4 + r];
#pragma unroll
        for (int w = 1; w < 16; ++w) m_ = fmaxf(m_, redm[w][lg * 4 + r]);
        gm[r] = m_;
    }

    // exp + row sum (same reduction path)
    float ps[4];
#pragma unroll
    for (int r = 0; r < 4; ++r) ps[r] = 0.f;
#pragma unroll
    for (int j = 0; j < 4; ++j)
#pragma unroll
        for (int r = 0; r < 4; ++r) {
            float e = EXP2F((lv[j][r] - gm[r]) * L2E);   // -3e38 -> 0
            lv[j][r] = e;
            ps[r] += e;
        }
#pragma unroll
    for (int r = 0; r < 4; ++r) {
        ps[r] += __shfl_xor(ps[r], 1);
        ps[r] += __shfl_xor(ps[r], 2);
        ps[r] += __shfl_xor(ps[r], 4);
        ps[r] += __shfl_xor(ps[r], 8);
    }
    if (lr == 0) {
#pragma unroll
        for (int r = 0; r < 4; ++r) reds[wave][lg * 4 + r] = ps[r];
    }
    __syncthreads();
    float inv[4];
#pragma unroll
    for (int r = 0; r < 4; ++r) {
        float s = 0.f;
#pragma unroll
        for (int w = 0; w < 16; ++w) s += reds[w][lg * 4 + r];
        inv[r] = 1.0f / s;
    }

    // normalized writes (each (b,p,n) exactly once)
#pragma unroll
    for (int j = 0; j < 4; ++j) {
        const int n = n0 + j * 16 + lr;
        if (n >= N_) continue;
#pragma unroll
        for (int r = 0; r < 4; ++r) {
            const int p = prowb + r;
            if (p >= P_) continue;
            out[((size_t)(b * P_ + p)) * N_ + n] = lv[j][r] * inv[r];
        }
    }
}

// ---------------------------------------------------------------------------
extern "C" void kernel_launch(void* const* d_in, const int* in_sizes, int n_in,
                              void* d_out, int out_size, void* d_ws, size_t ws_size,
                              hipStream_t stream)
{
    const float* lastnode = (const float*)d_in[0];   // [B,P,256]
    const float* attr     = (const float*)d_in[1];   // [B,P,4]
    const float* ctx      = (const float*)d_in[2];   // [B,1024]
    const float* mask     = (const float*)d_in[3];   // [B,P,N]
    const float* nodes    = (const float*)d_in[4];   // [B,N,256]
    const float* Wq       = (const float*)d_in[5];   // [1284,256]
    const float* Wk       = (const float*)d_in[6];   // [256,256]
    const float* Wv       = (const float*)d_in[7];   // [256,256]
    const float* Wcomb    = (const float*)d_in[8];   // [256,256]
    const float* bcomb    = (const float*)d_in[9];   // [256]
    float* out = (float*)d_out;

    // Workspace layout (offsets in floats). Total 27,230,208 f = 108.9 MB.
    float* ws = (float*)d_ws;
    bf16_t* kbuf   = (bf16_t*)(ws);                   // 16,384,000 bf16
    bf16_t* vbuf   = (bf16_t*)(ws + 8192000);         // 16,384,000 bf16
    float*  qbuf   = ws + 16384000;                   // 1,638,400 f
    bf16_t* nbf    = (bf16_t*)(ws + 18022400);        // 16,384,000 bf16
    bf16_t* WkT    = (bf16_t*)(ws + 26214400);        // 65,536 bf16
    bf16_t* WvT    = (bf16_t*)(ws + 26247168);        // 65,536 bf16
    bf16_t* WcombT = (bf16_t*)(ws + 26279936);        // 65,536 bf16
    bf16_t* WqmT   = (bf16_t*)(ws + 26312704);        // 65,536 bf16
    float*  qcpart = ws + 26345472;                   // 65,536 f (4x64x256)
    bf16_t* abuf   = (bf16_t*)(ws + 26411008);        // 1,638,400 bf16
    // Overlay: mhbuf reuses kbuf (K dead after attn_mfma); logits reads rows
    // up to b*100+111 -> slack is inside kbuf's 64000 rows.
    bf16_t* mhbuf = kbuf;

    // 1) weight transposes -> bf16 (Wk, Wv, Wcomb, Wq[0:256))
    wtrans_kernel<<<dim3(8, 8, 4), 256, 0, stream>>>(
        Wk, Wv, Wcomb, Wq, WkT, WvT, WcombT, WqmT);

    // 2) q pipeline: ctx partials + fused GEMM/fixup (f32 A, in-register cvt)
    qc_kernel<<<dim3(64, 4), 256, 0, stream>>>(ctx, Wq, qcpart);
    mfma_gemm_q<<<400, 256, 0, stream>>>(lastnode, WqmT, qcpart, attr, Wq, qbuf);

    // 3) fused k+v projection + nodes cvt (LDS-staged A, grid 1000)
    mfma_gemm_kv<<<1000, 256, 0, stream>>>(nodes, WkT, WvT, kbuf, vbuf, nbf);

    // 4) fused MFMA flash attention (cooperative LDS staging) -> abuf
    attn_mfma<<<448, 1024, 0, stream>>>(qbuf, kbuf, vbuf, mask, abuf);

    // 5) combine projection (MFMA, bias, bf16 out into mhbuf)
    mfma_gemm<true, true><<<400, 256, 0, stream>>>(abuf, WcombT, bcomb, mhbuf);

    // 6) fused pointer logits + softmax (bf16 nodes from nbf) -> out
    logits_softmax<<<448, 1024, 0, stream>>>(mhbuf, nbf, mask, out);
}

// Round 23
// 223.921 us; speedup vs baseline: 1.2894x; 1.0158x over previous
//
#include <hip/hip_runtime.h>
#include <hip/hip_bf16.h>
#include <math.h>

// Problem constants (from reference)
#define B_  64
#define P_  100
#define N_  1000
#define EMB_ 256
#define H_  16
#define D_  16
#define CTX_ 1024
#define L2E 1.44269504088896340736f
#define LROW 264   // kv LDS row stride (elems): 132 dwords = 4 mod 32 -> 2-way free
#define AROW 136   // attn LDS row stride (elems): 68 dwords = 4 mod 32 -> 2-way free

#if __has_builtin(__builtin_amdgcn_exp2f)
#define EXP2F(x) __builtin_amdgcn_exp2f(x)
#else
#define EXP2F(x) exp2f(x)
#endif

typedef __bf16 bf16_t;
typedef bf16_t bf16x8 __attribute__((ext_vector_type(8)));
typedef bf16_t bf16x4 __attribute__((ext_vector_type(4)));
typedef float  f32x4  __attribute__((ext_vector_type(4)));
typedef short  s16x4  __attribute__((ext_vector_type(4)));

// PV MFMA via builtin when available (R16-proven correct/neutral);
// asm fallback with manual hazard fences otherwise.
#if __has_builtin(__builtin_amdgcn_mfma_f32_16x16x16bf16_1k)
__device__ __forceinline__ void pv_mfma16(bf16x4 a, bf16x4 b, f32x4& c)
{
    s16x4 ai, bi;
    __builtin_memcpy(&ai, &a, 8);
    __builtin_memcpy(&bi, &b, 8);
    c = __builtin_amdgcn_mfma_f32_16x16x16bf16_1k(ai, bi, c, 0, 0, 0);
}
__device__ __forceinline__ void mfma_hazard_fence() {}
#else
__device__ __forceinline__ void pv_mfma16(bf16x4 a, bf16x4 b, f32x4& c)
{
    asm("s_nop 1\n\tv_mfma_f32_16x16x16_bf16 %0, %1, %2, %0"
        : "+v"(c) : "v"(a), "v"(b));
}
__device__ __forceinline__ void mfma_hazard_fence()
{
    __builtin_amdgcn_sched_barrier(0);
    asm volatile("s_nop 7\n\ts_nop 3");
}
#endif

// Load 8 consecutive f32 and convert to bf16x8 in-register.
__device__ __forceinline__ bf16x8 ldcvt8(const float* __restrict__ p)
{
    float4 u = *(const float4*)p;
    float4 v = *(const float4*)(p + 4);
    bf16x8 r;
    r[0] = (bf16_t)u.x; r[1] = (bf16_t)u.y; r[2] = (bf16_t)u.z; r[3] = (bf16_t)u.w;
    r[4] = (bf16_t)v.x; r[5] = (bf16_t)v.y; r[6] = (bf16_t)v.z; r[7] = (bf16_t)v.w;
    return r;
}

// ---------------------------------------------------------------------------
// Transpose four 256x256 f32 weights -> bf16 WT[n][k]
// ---------------------------------------------------------------------------
__global__ __launch_bounds__(256) void wtrans_kernel(
    const float* __restrict__ W0, const float* __restrict__ W1,
    const float* __restrict__ W2, const float* __restrict__ W3,
    bf16_t* __restrict__ T0, bf16_t* __restrict__ T1,
    bf16_t* __restrict__ T2, bf16_t* __restrict__ T3)
{
    __shared__ float t[32][33];
    const float* W = (blockIdx.z == 0) ? W0 : (blockIdx.z == 1) ? W1
                   : (blockIdx.z == 2) ? W2 : W3;
    bf16_t*      T = (blockIdx.z == 0) ? T0 : (blockIdx.z == 1) ? T1
                   : (blockIdx.z == 2) ? T2 : T3;
    const int n0 = blockIdx.x * 32, k0 = blockIdx.y * 32;
    const int tx = threadIdx.x & 31, ty = threadIdx.x >> 5;   // ty 0..7
#pragma unroll
    for (int i = 0; i < 4; ++i)
        t[ty + i * 8][tx] = W[(size_t)(k0 + ty + i * 8) * 256 + n0 + tx];
    __syncthreads();
#pragma unroll
    for (int i = 0; i < 4; ++i)
        T[(size_t)(n0 + ty + i * 8) * 256 + k0 + tx] = (bf16_t)t[tx][ty + i * 8];
}

// ---------------------------------------------------------------------------
// MFMA GEMM (bf16 A): C[M,256] = A[M,256] @ BT[256,256]^T.
// ---------------------------------------------------------------------------
template<bool BIAS, bool OUT_BF16>
__global__ __launch_bounds__(256) void mfma_gemm(
    const bf16_t* __restrict__ A, const bf16_t* __restrict__ BT,
    const float* __restrict__ bias, void* __restrict__ Cout)
{
    const int wave = threadIdx.x >> 6;
    const int lane = threadIdx.x & 63;
    const int m0 = blockIdx.x * 16;
    const int n0 = wave * 64;
    const int lr = lane & 15;
    const int lk = (lane >> 4) * 8;

    const bf16_t* ap = A  + (size_t)(m0 + lr) * 256 + lk;
    const bf16_t* bp = BT + (size_t)(n0 + lr) * 256 + lk;

    f32x4 acc[4];
#pragma unroll
    for (int j = 0; j < 4; ++j) acc[j] = (f32x4)0.f;

#pragma unroll 2
    for (int k0 = 0; k0 < 256; k0 += 32) {
        bf16x8 a = *(const bf16x8*)(ap + k0);
#pragma unroll
        for (int j = 0; j < 4; ++j) {
            bf16x8 b = *(const bf16x8*)(bp + (size_t)j * 16 * 256 + k0);
            acc[j] = __builtin_amdgcn_mfma_f32_16x16x32_bf16(a, b, acc[j], 0, 0, 0);
        }
    }

    const int crow = m0 + (lane >> 4) * 4;
#pragma unroll
    for (int j = 0; j < 4; ++j) {
        const int col = n0 + j * 16 + lr;
        const float bv = BIAS ? bias[col] : 0.f;
#pragma unroll
        for (int r = 0; r < 4; ++r) {
            float val = acc[j][r] + bv;
            if (OUT_BF16)
                ((bf16_t*)Cout)[(size_t)(crow + r) * 256 + col] = (bf16_t)val;
            else
                ((float*)Cout)[(size_t)(crow + r) * 256 + col] = val;
        }
    }
}

// ---------------------------------------------------------------------------
// q-path GEMM, f32 A with in-register cvt, fused fixup epilogue.
// ---------------------------------------------------------------------------
__global__ __launch_bounds__(256) void mfma_gemm_q(
    const float* __restrict__ A, const bf16_t* __restrict__ BT,
    const float* __restrict__ qcpart, const float* __restrict__ attr,
    const float* __restrict__ Wq, float* __restrict__ Cout)
{
    const int wave = threadIdx.x >> 6;
    const int lane = threadIdx.x & 63;
    const int m0 = blockIdx.x * 16;
    const int n0 = wave * 64;
    const int lr = lane & 15;
    const int lk = (lane >> 4) * 8;

    const float*  ap = A  + (size_t)(m0 + lr) * 256 + lk;
    const bf16_t* bp = BT + (size_t)(n0 + lr) * 256 + lk;

    f32x4 acc[4];
#pragma unroll
    for (int j = 0; j < 4; ++j) acc[j] = (f32x4)0.f;

#pragma unroll 2
    for (int k0 = 0; k0 < 256; k0 += 32) {
        bf16x8 a = ldcvt8(ap + k0);
#pragma unroll
        for (int j = 0; j < 4; ++j) {
            bf16x8 b = *(const bf16x8*)(bp + (size_t)j * 16 * 256 + k0);
            acc[j] = __builtin_amdgcn_mfma_f32_16x16x32_bf16(a, b, acc[j], 0, 0, 0);
        }
    }

    const int crow = m0 + (lane >> 4) * 4;
#pragma unroll
    for (int j = 0; j < 4; ++j) {
        const int col = n0 + j * 16 + lr;
#pragma unroll
        for (int r = 0; r < 4; ++r) {
            const int row = crow + r;         // < 6400
            const int b = row / P_;
            float add = 0.f;
#pragma unroll
            for (int kc = 0; kc < 4; ++kc)
                add += qcpart[((size_t)kc * 64 + b) * EMB_ + col];
            add = fmaf(attr[(size_t)row * 4 + 0], Wq[(size_t)256 * EMB_ + col], add);
            add = fmaf(attr[(size_t)row * 4 + 1], Wq[(size_t)257 * EMB_ + col], add);
            add = fmaf(attr[(size_t)row * 4 + 2], Wq[(size_t)258 * EMB_ + col], add);
            add = fmaf(attr[(size_t)row * 4 + 3], Wq[(size_t)259 * EMB_ + col], add);
            Cout[(size_t)row * 256 + col] = acc[j][r] + add;
        }
    }
}

// ---------------------------------------------------------------------------
// Fused K+V projection + nodes cvt (R21-proven WIN): cooperative LDS-staged A.
// ---------------------------------------------------------------------------
__global__ __launch_bounds__(256) void mfma_gemm_kv(
    const float* __restrict__ A, const bf16_t* __restrict__ BTk,
    const bf16_t* __restrict__ BTv,
    bf16_t* __restrict__ Ck, bf16_t* __restrict__ Cv,
    bf16_t* __restrict__ nbf)
{
    __shared__ bf16_t sA[64][LROW];          // 64 x 264 x 2B = 33,792 B

    const int tid  = threadIdx.x;
    const int wave = tid >> 6;
    const int lane = tid & 63;
    const int m0 = blockIdx.x * 64;          // grid 1000 (64000 rows)
    const int n0 = wave * 64;
    const int lr = lane & 15;
    const int lk = (lane >> 4) * 8;

    // cooperative A stage: 2048 chunks of 8 elems; 8 per thread, coalesced.
#pragma unroll
    for (int c = 0; c < 8; ++c) {
        const int chunk = tid + c * 256;     // 0..2047
        const int row = chunk >> 5;          // 0..63
        const int col = (chunk & 31) * 8;    // 0..248
        bf16x8 vv = ldcvt8(A + (size_t)(m0 + row) * 256 + col);
        *(bf16x8*)(&sA[row][col]) = vv;
        *(bf16x8*)(nbf + (size_t)(m0 + row) * 256 + col) = vv;   // fused cvt out
    }
    __syncthreads();

    const bf16_t* bpk = BTk + (size_t)(n0 + lr) * 256 + lk;
    const bf16_t* bpv = BTv + (size_t)(n0 + lr) * 256 + lk;

    f32x4 acck[4][4], accv[4][4];
#pragma unroll
    for (int m = 0; m < 4; ++m)
#pragma unroll
        for (int j = 0; j < 4; ++j) { acck[m][j] = (f32x4)0.f; accv[m][j] = (f32x4)0.f; }

    for (int k0 = 0; k0 < 256; k0 += 32) {
        bf16x8 a0 = *(const bf16x8*)(&sA[0 * 16 + lr][lk + k0]);
        bf16x8 a1 = *(const bf16x8*)(&sA[1 * 16 + lr][lk + k0]);
        bf16x8 a2 = *(const bf16x8*)(&sA[2 * 16 + lr][lk + k0]);
        bf16x8 a3 = *(const bf16x8*)(&sA[3 * 16 + lr][lk + k0]);
#pragma unroll
        for (int j = 0; j < 4; ++j) {
            bf16x8 bk = *(const bf16x8*)(bpk + (size_t)j * 16 * 256 + k0);
            bf16x8 bv = *(const bf16x8*)(bpv + (size_t)j * 16 * 256 + k0);
            // swapped: lane holds C[m0+m*16+lr][n0+j*16+4*lg .. +3]
            acck[0][j] = __builtin_amdgcn_mfma_f32_16x16x32_bf16(bk, a0, acck[0][j], 0, 0, 0);
            acck[1][j] = __builtin_amdgcn_mfma_f32_16x16x32_bf16(bk, a1, acck[1][j], 0, 0, 0);
            acck[2][j] = __builtin_amdgcn_mfma_f32_16x16x32_bf16(bk, a2, acck[2][j], 0, 0, 0);
            acck[3][j] = __builtin_amdgcn_mfma_f32_16x16x32_bf16(bk, a3, acck[3][j], 0, 0, 0);
            accv[0][j] = __builtin_amdgcn_mfma_f32_16x16x32_bf16(bv, a0, accv[0][j], 0, 0, 0);
            accv[1][j] = __builtin_amdgcn_mfma_f32_16x16x32_bf16(bv, a1, accv[1][j], 0, 0, 0);
            accv[2][j] = __builtin_amdgcn_mfma_f32_16x16x32_bf16(bv, a2, accv[2][j], 0, 0, 0);
            accv[3][j] = __builtin_amdgcn_mfma_f32_16x16x32_bf16(bv, a3, accv[3][j], 0, 0, 0);
        }
    }

    const int lg4 = (lane >> 4) * 4;
#pragma unroll
    for (int m = 0; m < 4; ++m) {
        const size_t rowoff = (size_t)(m0 + m * 16 + lr) * 256;
#pragma unroll
        for (int j = 0; j < 4; ++j) {
            const int col = n0 + j * 16 + lg4;
            bf16x4 ok, ov;
#pragma unroll
            for (int r = 0; r < 4; ++r) {
                ok[r] = (bf16_t)acck[m][j][r];
                ov[r] = (bf16_t)accv[m][j][r];
            }
            *(bf16x4*)(Ck + rowoff + col) = ok;
            *(bf16x4*)(Cv + rowoff + col) = ov;
        }
    }
}

// ---------------------------------------------------------------------------
// qc partials: qcpart[kc][b][n] = sum_{k in chunk kc} ctx[b][k]*Wq[260+k][n]
// ---------------------------------------------------------------------------
__global__ __launch_bounds__(256) void qc_kernel(
    const float* __restrict__ ctx, const float* __restrict__ Wq,
    float* __restrict__ qcpart)
{
    const int b = blockIdx.x;
    const int kc = blockIdx.y;
    const int tid = threadIdx.x;
    const float* c = ctx + (size_t)b * CTX_ + kc * 256;
    const float* w = Wq + (size_t)(260 + kc * 256) * EMB_ + tid;
    float acc = 0.f;
#pragma unroll 8
    for (int kk = 0; kk < 256; ++kk)
        acc = fmaf(c[kk], w[(size_t)kk * EMB_], acc);
    qcpart[((size_t)kc * 64 + b) * EMB_ + tid] = acc;
}

// ---------------------------------------------------------------------------
// MFMA flash attention v22: 512-thread head-group blocks (R22).
// Block = (b, mtile, hgroup of 8 heads); stages only its hgroup's 128
// COLUMNS of K/V (no traffic duplication), LDS 17.4KB -> 4 blocks/CU
// (was 2) so one block's barrier drain hides under 3 others' compute.
// Cooperative double-buffered staging as R20/R21. Grid 896 x 512.
// ---------------------------------------------------------------------------
struct AttnState { float m, l; f32x4 acc; };

template<bool TAIL>
__device__ __forceinline__ void attn_chunk_lds(
    int n0, const bf16_t* __restrict__ skb, const bf16_t* __restrict__ svb,
    const float* __restrict__ maskrow, bf16x8 qfrag, int hl, int lr, int lg,
    AttnState& st)
{
    // K A-frag from LDS: row lr, cols hl*16 + (lg&1)*8 .. +8 ; zero for lg>=2
    bf16x8 ak = *(const bf16x8*)(skb + lr * AROW + hl * 16 + (lg & 1) * 8);
    if (lg >= 2) ak = (bf16x8)(bf16_t)0.0f;

    f32x4 sc = __builtin_amdgcn_mfma_f32_16x16x32_bf16(ak, qfrag, (f32x4)0.f, 0, 0, 0);

    // scores + mask (lane's 4 keys n = n0+4*lg+r, query p = lr)
    int nm = n0 + 4 * lg;
    if (TAIL) nm = (nm < 996) ? nm : 996;
    float4 mk = *(const float4*)&maskrow[nm];
    float s0 = fmaf(sc[0], 0.25f, mk.x);
    float s1 = fmaf(sc[1], 0.25f, mk.y);
    float s2 = fmaf(sc[2], 0.25f, mk.z);
    float s3 = fmaf(sc[3], 0.25f, mk.w);
    if (TAIL) {
        if (n0 + 4 * lg + 0 >= N_) s0 = -3.0e38f;
        if (n0 + 4 * lg + 1 >= N_) s1 = -3.0e38f;
        if (n0 + 4 * lg + 2 >= N_) s2 = -3.0e38f;
        if (n0 + 4 * lg + 3 >= N_) s3 = -3.0e38f;
    }

    // defer-max: common path is per-lane only (no cross-lane ops)
    float tmax = fmaxf(fmaxf(s0, s1), fmaxf(s2, s3));
    if (__any(tmax > st.m + 8.0f)) {        // rare (~once per state)
        float rmax = fmaxf(tmax, __shfl_xor(tmax, 16));
        rmax = fmaxf(rmax, __shfl_xor(rmax, 32));
        float mn = fmaxf(st.m, rmax);
        mfma_hazard_fence();                // no-op on builtin path
        float f = EXP2F((st.m - mn) * L2E); // first time: exp2(-inf)=0
        st.l *= f;
        st.acc *= f;
        st.m = mn;
    }
    float w0 = EXP2F((s0 - st.m) * L2E);    // bounded by e^8
    float w1 = EXP2F((s1 - st.m) * L2E);
    float w2 = EXP2F((s2 - st.m) * L2E);
    float w3 = EXP2F((s3 - st.m) * L2E);
    st.l += (w0 + w1) + (w2 + w3);
    bf16x4 pb;
    pb[0] = (bf16_t)w0; pb[1] = (bf16_t)w1; pb[2] = (bf16_t)w2; pb[3] = (bf16_t)w3;

    // V^T A-frag from LDS: rows 4*lg..4*lg+3, col hl*16+lr
    bf16x4 av;
#pragma unroll
    for (int i = 0; i < 4; ++i)
        av[i] = svb[(4 * lg + i) * AROW + hl * 16 + lr];
    pv_mfma16(av, pb, st.acc);
}

__global__ __launch_bounds__(512) void attn_mfma(
    const float* __restrict__ q, const bf16_t* __restrict__ k,
    const bf16_t* __restrict__ v, const float* __restrict__ mask,
    bf16_t* __restrict__ abuf)
{
    __shared__ bf16_t sk[2][16][AROW];   // 2 x 16 x 136 x 2B = 8,704 B
    __shared__ bf16_t sv[2][16][AROW];   // total 17,408 B

    // XCD-bijective: 896 = 8 xcd * 112; 112 = 8 bgroups * 7 mtiles * 2 hgrps
    const int x = blockIdx.x;
    const int xcd = x & 7;
    const int slot = x >> 3;                 // 0..111
    const int b = xcd + 8 * (slot / 14);
    const int rem = slot % 14;
    const int mtile = rem >> 1;              // 0..6
    const int hg = rem & 1;                  // head group: heads hg*8..hg*8+7
    const int hl = threadIdx.x >> 6;         // local head 0..7
    const int h = hg * 8 + hl;
    const int lane = threadIdx.x & 63;
    const int p0 = mtile * 16;
    const int lr = lane & 15;
    const int lg = lane >> 4;

    // staging role (512 threads): half 0 stages K cols, half 1 stages V cols
    const int tid = threadIdx.x;
    const int sh  = tid >> 8;                // 0 = K, 1 = V
    const int t2  = tid & 255;
    const int srow = t2 >> 4;                // 0..15
    const int scol = (t2 & 15) * 8;          // 0..120 (within the 128-col slab)

    // Q B-frag (x32): col p = lr, k(d) = 8*lg+i ; zero for lg>=2
    const int pq = (p0 + lr < P_) ? (p0 + lr) : (P_ - 1);
    bf16x8 qfrag = (bf16x8)(bf16_t)0.0f;
    if (lg < 2) {
        const float* qp = q + ((size_t)b * P_ + pq) * 256 + h * 16 + lg * 8;
        float4 q0 = *(const float4*)qp;
        float4 q1 = *(const float4*)(qp + 4);
        qfrag[0] = (bf16_t)q0.x; qfrag[1] = (bf16_t)q0.y;
        qfrag[2] = (bf16_t)q0.z; qfrag[3] = (bf16_t)q0.w;
        qfrag[4] = (bf16_t)q1.x; qfrag[5] = (bf16_t)q1.y;
        qfrag[6] = (bf16_t)q1.z; qfrag[7] = (bf16_t)q1.w;
    }

    const bf16_t* kfull = k + (size_t)b * N_ * 256 + hg * 128;
    const bf16_t* vfull = v + (size_t)b * N_ * 256 + hg * 128;
    const bf16_t* sbase = sh ? vfull : kfull;
    const float* maskrow = mask + ((size_t)b * P_ + pq) * N_;

    AttnState stA, stB;
    stA.m = -INFINITY; stA.l = 0.f; stA.acc = (f32x4)0.f;
    stB.m = -INFINITY; stB.l = 0.f; stB.acc = (f32x4)0.f;

    // prologue: stage chunk 0 into buf 0
    {
        const bf16_t* src = sbase + (size_t)srow * 256 + scol;
        bf16_t* dst = sh ? &sv[0][srow][scol] : &sk[0][srow][scol];
        *(bf16x8*)dst = *(const bf16x8*)src;
    }
    __syncthreads();

    // 63 chunks total; chunks 0..61 in the loop, chunk 62 (tail) after.
    for (int it = 0; it < 62; ++it) {
        // stage chunk it+1 into the other buffer (rows clamped for tail)
        {
            const int rr = min((it + 1) * 16 + srow, N_ - 1);
            const bf16_t* src = sbase + (size_t)rr * 256 + scol;
            bf16_t* dst = sh ? &sv[(it + 1) & 1][srow][scol]
                             : &sk[(it + 1) & 1][srow][scol];
            *(bf16x8*)dst = *(const bf16x8*)src;
        }
        // compute chunk it from buf[it&1]; even chunks -> A, odd -> B
        if (it & 1)
            attn_chunk_lds<false>(it * 16, &sk[it & 1][0][0], &sv[it & 1][0][0],
                                  maskrow, qfrag, hl, lr, lg, stB);
        else
            attn_chunk_lds<false>(it * 16, &sk[it & 1][0][0], &sv[it & 1][0][0],
                                  maskrow, qfrag, hl, lr, lg, stA);
        __syncthreads();
    }
    // tail chunk 62 (n0=992) from buf 0 (staged at it=61; rows >=1000 are
    // clamped dup data, zeroed by the TAIL score masking)
    attn_chunk_lds<true>(992, &sk[0][0][0], &sv[0][0][0],
                         maskrow, qfrag, hl, lr, lg, stA);

    // merge the two states (flash combine)
    mfma_hazard_fence();                      // no-op on builtin path
    float mn = fmaxf(stA.m, stB.m);
    float fA = EXP2F((stA.m - mn) * L2E);
    float fB = EXP2F((stB.m - mn) * L2E);
    float l = stA.l * fA + stB.l * fB;
    f32x4 acc = stA.acc * fA + stB.acc * fB;

    // row sum of l across the 4 lanes sharing lr
    float L = l + __shfl_xor(l, 16);
    L += __shfl_xor(L, 32);

    if (p0 + lr < P_) {
        float inv = 1.0f / L;
        bf16x4 o;
        o[0] = (bf16_t)(acc[0] * inv);
        o[1] = (bf16_t)(acc[1] * inv);
        o[2] = (bf16_t)(acc[2] * inv);
        o[3] = (bf16_t)(acc[3] * inv);
        // out^T: lane holds out[p=lr][d=4*lg+r]
        *(bf16x4*)(abuf + ((size_t)b * P_ + p0 + lr) * 256 + h * 16 + 4 * lg) = o;
    }
}

// ---------------------------------------------------------------------------
// Fused pointer logits + row softmax (bf16 nodes operand). Grid 448 x 1024.
// ---------------------------------------------------------------------------
__global__ __launch_bounds__(1024) void logits_softmax(
    const bf16_t* __restrict__ mh, const bf16_t* __restrict__ nodes,
    const float* __restrict__ mask, float* __restrict__ out)
{
    __shared__ float redm[16][16];
    __shared__ float reds[16][16];

    // XCD-bijective: 448 = 8 xcd * 56; 56 = 8 b-groups * 7 mtiles
    const int x = blockIdx.x;
    const int xcd = x & 7;
    const int slot = x >> 3;                 // 0..55
    const int b = xcd + 8 * (slot / 7);
    const int mt = slot % 7;
    const int wave = threadIdx.x >> 6;       // ngrp 0..15
    const int lane = threadIdx.x & 63;
    const int p0 = mt * 16;
    const int n0 = wave * 64;
    const int lr = lane & 15;
    const int lg = lane >> 4;
    const int lk = lg * 8;

    const bf16_t* bbase = nodes + (size_t)b * N_ * 256;
    int nrow[4];
#pragma unroll
    for (int j = 0; j < 4; ++j) {
        int n = n0 + j * 16 + lr;
        nrow[j] = (n < N_) ? n : (N_ - 1);
    }
    const bf16_t* ap = mh + ((size_t)(b * P_) + p0 + lr) * 256 + lk;

    f32x4 acc[4];
#pragma unroll
    for (int j = 0; j < 4; ++j) acc[j] = (f32x4)0.f;

#pragma unroll 2
    for (int k0 = 0; k0 < 256; k0 += 32) {
        bf16x8 a = *(const bf16x8*)(ap + k0);
#pragma unroll
        for (int j = 0; j < 4; ++j) {
            bf16x8 bfr = *(const bf16x8*)(bbase + (size_t)nrow[j] * 256 + lk + k0);
            acc[j] = __builtin_amdgcn_mfma_f32_16x16x32_bf16(a, bfr, acc[j], 0, 0, 0);
        }
    }

    // logits: 10*tanh(s/16) + mask; invalid n -> -3e38 (excluded from softmax)
    const int prowb = p0 + lg * 4;
    float lv[4][4];
#pragma unroll
    for (int j = 0; j < 4; ++j) {
        const int n = n0 + j * 16 + lr;
        const int nc = (n < N_) ? n : (N_ - 1);
#pragma unroll
        for (int r = 0; r < 4; ++r) {
            const int p = prowb + r;
            const int pc = (p < P_) ? p : (P_ - 1);
            float xv = acc[j][r] * (1.0f / 16.0f);
            float e = EXP2F(xv * (2.0f * L2E));
            float t = 1.0f - 2.0f / (e + 1.0f);
            float val = 10.0f * t + mask[((size_t)(b * P_ + pc)) * N_ + nc];
            lv[j][r] = (n < N_) ? val : -3.0e38f;
        }
    }

    // row max: over j (in-thread), lr (shfl within 16-lane group), waves (LDS)
    float pm[4];
#pragma unroll
    for (int r = 0; r < 4; ++r) {
        pm[r] = fmaxf(fmaxf(lv[0][r], lv[1][r]), fmaxf(lv[2][r], lv[3][r]));
        pm[r] = fmaxf(pm[r], __shfl_xor(pm[r], 1));
        pm[r] = fmaxf(pm[r], __shfl_xor(pm[r], 2));
        pm[r] = fmaxf(pm[r], __shfl_xor(pm[r], 4));
        pm[r] = fmaxf(pm[r], __shfl_xor(pm[r], 8));
    }
    if (lr == 0) {
#pragma unroll
        for (int r = 0; r < 4; ++r) redm[wave][lg * 4 + r] = pm[r];
    }
    __syncthreads();
    float gm[4];
#pragma unroll
    for (int r = 0; r < 4; ++r) {
        float m_ = redm[0][lg * 4 + r];
#pragma unroll
        for (int w = 1; w < 16; ++w) m_ = fmaxf(m_, redm[w][lg * 4 + r]);
        gm[r] = m_;
    }

    // exp + row sum (same reduction path)
    float ps[4];
#pragma unroll
    for (int r = 0; r < 4; ++r) ps[r] = 0.f;
#pragma unroll
    for (int j = 0; j < 4; ++j)
#pragma unroll
        for (int r = 0; r < 4; ++r) {
            float e = EXP2F((lv[j][r] - gm[r]) * L2E);   // -3e38 -> 0
            lv[j][r] = e;
            ps[r] += e;
        }
#pragma unroll
    for (int r = 0; r < 4; ++r) {
        ps[r] += __shfl_xor(ps[r], 1);
        ps[r] += __shfl_xor(ps[r], 2);
        ps[r] += __shfl_xor(ps[r], 4);
        ps[r] += __shfl_xor(ps[r], 8);
    }
    if (lr == 0) {
#pragma unroll
        for (int r = 0; r < 4; ++r) reds[wave][lg * 4 + r] = ps[r];
    }
    __syncthreads();
    float inv[4];
#pragma unroll
    for (int r = 0; r < 4; ++r) {
        float s = 0.f;
#pragma unroll
        for (int w = 0; w < 16; ++w) s += reds[w][lg * 4 + r];
        inv[r] = 1.0f / s;
    }

    // normalized writes (each (b,p,n) exactly once)
#pragma unroll
    for (int j = 0; j < 4; ++j) {
        const int n = n0 + j * 16 + lr;
        if (n >= N_) continue;
#pragma unroll
        for (int r = 0; r < 4; ++r) {
            const int p = prowb + r;
            if (p >= P_) continue;
            out[((size_t)(b * P_ + p)) * N_ + n] = lv[j][r] * inv[r];
        }
    }
}

// ---------------------------------------------------------------------------
extern "C" void kernel_launch(void* const* d_in, const int* in_sizes, int n_in,
                              void* d_out, int out_size, void* d_ws, size_t ws_size,
                              hipStream_t stream)
{
    const float* lastnode = (const float*)d_in[0];   // [B,P,256]
    const float* attr     = (const float*)d_in[1];   // [B,P,4]
    const float* ctx      = (const float*)d_in[2];   // [B,1024]
    const float* mask     = (const float*)d_in[3];   // [B,P,N]
    const float* nodes    = (const float*)d_in[4];   // [B,N,256]
    const float* Wq       = (const float*)d_in[5];   // [1284,256]
    const float* Wk       = (const float*)d_in[6];   // [256,256]
    const float* Wv       = (const float*)d_in[7];   // [256,256]
    const float* Wcomb    = (const float*)d_in[8];   // [256,256]
    const float* bcomb    = (const float*)d_in[9];   // [256]
    float* out = (float*)d_out;

    // Workspace layout (offsets in floats). Total 27,230,208 f = 108.9 MB.
    float* ws = (float*)d_ws;
    bf16_t* kbuf   = (bf16_t*)(ws);                   // 16,384,000 bf16
    bf16_t* vbuf   = (bf16_t*)(ws + 8192000);         // 16,384,000 bf16
    float*  qbuf   = ws + 16384000;                   // 1,638,400 f
    bf16_t* nbf    = (bf16_t*)(ws + 18022400);        // 16,384,000 bf16
    bf16_t* WkT    = (bf16_t*)(ws + 26214400);        // 65,536 bf16
    bf16_t* WvT    = (bf16_t*)(ws + 26247168);        // 65,536 bf16
    bf16_t* WcombT = (bf16_t*)(ws + 26279936);        // 65,536 bf16
    bf16_t* WqmT   = (bf16_t*)(ws + 26312704);        // 65,536 bf16
    float*  qcpart = ws + 26345472;                   // 65,536 f (4x64x256)
    bf16_t* abuf   = (bf16_t*)(ws + 26411008);        // 1,638,400 bf16
    // Overlay: mhbuf reuses kbuf (K dead after attn_mfma); logits reads rows
    // up to b*100+111 -> slack is inside kbuf's 64000 rows.
    bf16_t* mhbuf = kbuf;

    // 1) weight transposes -> bf16 (Wk, Wv, Wcomb, Wq[0:256))
    wtrans_kernel<<<dim3(8, 8, 4), 256, 0, stream>>>(
        Wk, Wv, Wcomb, Wq, WkT, WvT, WcombT, WqmT);

    // 2) q pipeline: ctx partials + fused GEMM/fixup (f32 A, in-register cvt)
    qc_kernel<<<dim3(64, 4), 256, 0, stream>>>(ctx, Wq, qcpart);
    mfma_gemm_q<<<400, 256, 0, stream>>>(lastnode, WqmT, qcpart, attr, Wq, qbuf);

    // 3) fused k+v projection + nodes cvt (LDS-staged A, grid 1000)
    mfma_gemm_kv<<<1000, 256, 0, stream>>>(nodes, WkT, WvT, kbuf, vbuf, nbf);

    // 4) fused MFMA flash attention (512-thr head-group blocks) -> abuf
    attn_mfma<<<896, 512, 0, stream>>>(qbuf, kbuf, vbuf, mask, abuf);

    // 5) combine projection (MFMA, bias, bf16 out into mhbuf)
    mfma_gemm<true, true><<<400, 256, 0, stream>>>(abuf, WcombT, bcomb, mhbuf);

    // 6) fused pointer logits + softmax (bf16 nodes from nbf) -> out
    logits_softmax<<<448, 1024, 0, stream>>>(mhbuf, nbf, mask, out);
}